// Round 1
// baseline (770.932 us; speedup 1.0000x reference)
//
#include <hip/hip_runtime.h>

#define SEQ 4096
#define DMODEL 512
#define NH 8
#define DH 64
#define MLM 256
#define NBH 64          // B*H = 8*8
#define NROWS 32768     // B*SEQ

typedef unsigned short bf16_t;
typedef __attribute__((ext_vector_type(8))) short bf16x8;
typedef __attribute__((ext_vector_type(4))) float f32x4;

__device__ __forceinline__ float bf2f(unsigned short u) {
  return __uint_as_float(((unsigned)u) << 16);
}
__device__ __forceinline__ unsigned short f2bf(float f) {
  unsigned u = __float_as_uint(f);
  u += 0x7fffu + ((u >> 16) & 1u);
  return (unsigned short)(u >> 16);
}
// unpack 8 consecutive bf16 at p into d[0..7]
__device__ __forceinline__ void unp8(const bf16_t* p, float* d) {
  uint4 u = *(const uint4*)p;
  d[0] = __uint_as_float(u.x << 16); d[1] = __uint_as_float(u.x & 0xffff0000u);
  d[2] = __uint_as_float(u.y << 16); d[3] = __uint_as_float(u.y & 0xffff0000u);
  d[4] = __uint_as_float(u.z << 16); d[5] = __uint_as_float(u.z & 0xffff0000u);
  d[6] = __uint_as_float(u.w << 16); d[7] = __uint_as_float(u.w & 0xffff0000u);
}

// async global->LDS, 16B per lane, wave-uniform LDS base + lane*16 (m104)
__device__ __forceinline__ void gll16(const void* g, void* l) {
  __builtin_amdgcn_global_load_lds(
      (const __attribute__((address_space(1))) unsigned int*)g,
      (__attribute__((address_space(3))) unsigned int*)l, 16, 0, 0);
}

// ---------------------------------------------------------------- LayerNorm
__global__ __launch_bounds__(64) void ln_kernel(const float* __restrict__ x,
    const float* __restrict__ gamma, const float* __restrict__ beta,
    bf16_t* __restrict__ xn) {
  int row = blockIdx.x;
  const float4* xr = (const float4*)(x + (size_t)row * DMODEL);
  int t = threadIdx.x;
  float4 a = xr[t], b = xr[t + 64];
  float s  = a.x + a.y + a.z + a.w + b.x + b.y + b.z + b.w;
  float ss = a.x*a.x + a.y*a.y + a.z*a.z + a.w*a.w
           + b.x*b.x + b.y*b.y + b.z*b.z + b.w*b.w;
#pragma unroll
  for (int off = 32; off > 0; off >>= 1) {
    s  += __shfl_xor(s, off);
    ss += __shfl_xor(ss, off);
  }
  float mean = s * (1.0f / DMODEL);
  float var  = ss * (1.0f / DMODEL) - mean * mean;
  float rstd = rsqrtf(var + 1e-5f);
  const float4* g4 = (const float4*)gamma;
  const float4* be4 = (const float4*)beta;
  ushort4* o = (ushort4*)(xn + (size_t)row * DMODEL);
  float4 g = g4[t], bb = be4[t];
  ushort4 r;
  r.x = f2bf((a.x - mean) * rstd * g.x + bb.x);
  r.y = f2bf((a.y - mean) * rstd * g.y + bb.y);
  r.z = f2bf((a.z - mean) * rstd * g.z + bb.z);
  r.w = f2bf((a.w - mean) * rstd * g.w + bb.w);
  o[t] = r;
  g = g4[t + 64]; bb = be4[t + 64];
  r.x = f2bf((b.x - mean) * rstd * g.x + bb.x);
  r.y = f2bf((b.y - mean) * rstd * g.y + bb.y);
  r.z = f2bf((b.z - mean) * rstd * g.z + bb.z);
  r.w = f2bf((b.w - mean) * rstd * g.w + bb.w);
  o[t + 64] = r;
}

// ------------------------------------- weight convert + transpose (fp32->bf16)
__global__ __launch_bounds__(256) void convT(const float* __restrict__ w,
    bf16_t* __restrict__ wt, int K, int N) {
  size_t idx = (size_t)blockIdx.x * 256 + threadIdx.x;
  int n = (int)(idx / K), k = (int)(idx % K);
  wt[idx] = f2bf(w[(size_t)k * N + n]);
}

// ----------------------- MFMA 128x128 tile GEMM body (A, BT bf16 row-major-K)
// r-new: global_load_lds width-16 staging (m97 structure). LDS must be
// UNPADDED [128][32]: wave w lane l -> byte 1024*w + 16*l, which matches
// ar0 = tid>>2 / ac0 = (tid&3)*8 exactly. No reg round-trip, no ds_write.
#define MFMA_GEMM_BODY(APTR, BTPTR, KDIM) \
  __shared__ short As[128][32]; \
  __shared__ short Bs[128][32]; \
  int tid = threadIdx.x; \
  int lane = tid & 63; \
  int wv = tid >> 6; \
  int wm = (wv & 1) << 6, wn = (wv >> 1) << 6; \
  int l15 = lane & 15, l16 = lane >> 4; \
  f32x4 acc[4][4]; \
  _Pragma("unroll") for (int fm = 0; fm < 4; ++fm) \
    _Pragma("unroll") for (int fn = 0; fn < 4; ++fn) \
      acc[fm][fn] = (f32x4){0.f, 0.f, 0.f, 0.f}; \
  int ar0 = tid >> 2, ac0 = (tid & 3) << 3; \
  const bf16_t* Ab  = (APTR) + (size_t)(m0 + ar0) * (KDIM) + ac0; \
  const bf16_t* Ab1 = (APTR) + (size_t)(m0 + ar0 + 64) * (KDIM) + ac0; \
  const bf16_t* Bb  = (BTPTR) + (size_t)(n0 + ar0) * (KDIM) + ac0; \
  const bf16_t* Bb1 = (BTPTR) + (size_t)(n0 + ar0 + 64) * (KDIM) + ac0; \
  short* AsW  = &As[(wv << 4)][0]; \
  short* AsW1 = &As[64 + (wv << 4)][0]; \
  short* BsW  = &Bs[(wv << 4)][0]; \
  short* BsW1 = &Bs[64 + (wv << 4)][0]; \
  for (int k0 = 0; k0 < (KDIM); k0 += 32) { \
    gll16(Ab + k0, AsW);  gll16(Ab1 + k0, AsW1); \
    gll16(Bb + k0, BsW);  gll16(Bb1 + k0, BsW1); \
    __syncthreads(); \
    bf16x8 af[4], bfr[4]; \
    _Pragma("unroll") for (int f = 0; f < 4; ++f) { \
      af[f]  = *(const bf16x8*)&As[wm + f * 16 + l15][l16 * 8]; \
      bfr[f] = *(const bf16x8*)&Bs[wn + f * 16 + l15][l16 * 8]; \
    } \
    _Pragma("unroll") for (int fm = 0; fm < 4; ++fm) \
      _Pragma("unroll") for (int fn = 0; fn < 4; ++fn) \
        acc[fm][fn] = __builtin_amdgcn_mfma_f32_16x16x32_bf16(af[fm], bfr[fn], acc[fm][fn], 0, 0, 0); \
    __syncthreads(); \
  }

// QKV projection (MFMA), XCD-swizzled, r7 scalar epilogue (measured faster
// than the r8 LDS-staged variant: 100.5 vs 115.7 us).
__global__ __launch_bounds__(256) void gemm_qkv_mfma(const bf16_t* __restrict__ A,
    const bf16_t* __restrict__ BT, bf16_t* __restrict__ q, bf16_t* __restrict__ k,
    bf16_t* __restrict__ v, bf16_t* __restrict__ vT) {
  int bid = blockIdx.x;                        // 0..3071 (3072 % 8 == 0)
  int orig = (bid & 7) * 384 + (bid >> 3);     // XCD-contiguous remap
  int n0 = (orig % 12) << 7;
  int m0 = (orig / 12) << 7;
  MFMA_GEMM_BODY(A, BT, 512)
#pragma unroll
  for (int fm = 0; fm < 4; ++fm) {
    int row0 = m0 + wm + fm * 16 + l16 * 4;
    int bat = row0 >> 12;
    int nn0 = row0 & 4095;
#pragma unroll
    for (int fn = 0; fn < 4; ++fn) {
      int col = n0 + wn + fn * 16 + l15;
      int which = col >> 9;
      int hd = (col >> 6) & 7;
      int d  = col & 63;
      if (which == 2) {
        ushort4 pk;
        pk.x = f2bf(acc[fm][fn][0]); pk.y = f2bf(acc[fm][fn][1]);
        pk.z = f2bf(acc[fm][fn][2]); pk.w = f2bf(acc[fm][fn][3]);
        *(ushort4*)(vT + ((size_t)(bat * NH + hd) * DH + d) * SEQ + nn0) = pk;
#pragma unroll
        for (int rg = 0; rg < 4; ++rg)
          v[(((size_t)(bat * NH + hd)) * SEQ + nn0 + rg) * DH + d] = f2bf(acc[fm][fn][rg]);
      } else {
        bf16_t* dst = (which == 0) ? q : k;
        float scale = (which == 0) ? 0.125f : 1.f;
#pragma unroll
        for (int rg = 0; rg < 4; ++rg)
          dst[(((size_t)(bat * NH + hd)) * SEQ + nn0 + rg) * DH + d] = f2bf(acc[fm][fn][rg] * scale);
      }
    }
  }
}

// Output projection (MFMA), XCD-swizzled: y = x + om(bf16) @ woutT^T + b_out
__global__ __launch_bounds__(256) void gemm_out_mfma(const bf16_t* __restrict__ A,
    const bf16_t* __restrict__ BT, const float* __restrict__ bias,
    const float* __restrict__ x, float* __restrict__ y) {
  int bid = blockIdx.x;                        // 0..1023
  int orig = (bid & 7) * 128 + (bid >> 3);     // XCD-contiguous remap
  int n0 = (orig & 3) << 7;
  int m0 = (orig >> 2) << 7;
  MFMA_GEMM_BODY(A, BT, 512)
#pragma unroll
  for (int fm = 0; fm < 4; ++fm) {
#pragma unroll
    for (int fn = 0; fn < 4; ++fn) {
      int col = n0 + wn + fn * 16 + l15;
      float bv = bias[col];
#pragma unroll
      for (int rg = 0; rg < 4; ++rg) {
        int row = m0 + wm + fm * 16 + l16 * 4 + rg;
        y[(size_t)row * DMODEL + col] = x[(size_t)row * DMODEL + col] + acc[fm][fn][rg] + bv;
      }
    }
  }
}

// ---- 32x32-tile batched MFMA GEMM over 256x256 matrices.
// 1-D grid NBH*64 = 4096 blocks, bh-contiguous XCD swizzle (per-XCD working
// set = 8 bh x 256KB = 2MB < 4MB L2). 256 thr = 4 waves, each owning one
// 16x16 quadrant. Same K=32 MFMA chain per output element as the 64/128-tile
// bodies -> bitwise-identical numerics.
__global__ __launch_bounds__(256) void bmm_mfma32(const bf16_t* __restrict__ Ag,
    const bf16_t* __restrict__ BTg, bf16_t* __restrict__ Cb,
    bf16_t* __restrict__ CTb, float* __restrict__ Cf,
    int K, float alpha, float eA, float diagc, int flags) {
  int bid = blockIdx.x;                       // 0..4095
  int orig = (bid & 7) * 512 + (bid >> 3);    // XCD-contiguous remap
  int bh = orig >> 6;
  int tile = orig & 63;
  int n0 = (tile & 7) << 5;
  int m0 = (tile >> 3) << 5;
  const bf16_t* A  = Ag + (size_t)bh * 256 * K;
  const bf16_t* BT = BTg + (size_t)bh * 256 * K;
  __shared__ short As[32][36];
  __shared__ short Bs[32][36];
  int tid = threadIdx.x;
  int lane = tid & 63;
  int wv = tid >> 6;
  int wm = (wv & 1) << 4, wn = (wv >> 1) << 4;
  int l15 = lane & 15, l16 = lane >> 4;
  f32x4 acc = (f32x4){0.f, 0.f, 0.f, 0.f};
  int ar0 = tid >> 3, ac0 = (tid & 7) << 2;
  const bf16_t* Ab = A + (size_t)(m0 + ar0) * K + ac0;
  const bf16_t* Bb = BT + (size_t)(n0 + ar0) * K + ac0;
  uint2 ga = *(const uint2*)Ab;
  uint2 gb = *(const uint2*)Bb;
  for (int k0 = 0; k0 < K; k0 += 32) {
    *(uint2*)&As[ar0][ac0] = ga;
    *(uint2*)&Bs[ar0][ac0] = gb;
    __syncthreads();
    if (k0 + 32 < K) {
      ga = *(const uint2*)(Ab + k0 + 32);
      gb = *(const uint2*)(Bb + k0 + 32);
    }
    bf16x8 af = *(const bf16x8*)&As[wm + l15][l16 * 8];
    bf16x8 bf = *(const bf16x8*)&Bs[wn + l15][l16 * 8];
    acc = __builtin_amdgcn_mfma_f32_16x16x32_bf16(af, bf, acc, 0, 0, 0);
    __syncthreads();
  }
  size_t cbase = (size_t)bh * 65536;
  int row0 = m0 + wm + l16 * 4;
  int col = n0 + wn + l15;
  float v4[4];
#pragma unroll
  for (int rg = 0; rg < 4; ++rg) {
    float val = alpha * acc[rg];
    if (eA != 0.f) val += eA * bf2f(A[(size_t)(row0 + rg) * K + col]);
    if (row0 + rg == col) val += diagc;
    v4[rg] = val;
  }
  if (flags & 1) {
#pragma unroll
    for (int rg = 0; rg < 4; ++rg)
      Cb[cbase + (size_t)(row0 + rg) * 256 + col] = f2bf(v4[rg]);
  }
  if (flags & 2) {
    ushort4 pk;
    pk.x = f2bf(v4[0]); pk.y = f2bf(v4[1]);
    pk.z = f2bf(v4[2]); pk.w = f2bf(v4[3]);
    *(ushort4*)(CTb + cbase + (size_t)col * 256 + row0) = pk;
  }
  if (flags & 4) {
#pragma unroll
    for (int rg = 0; rg < 4; ++rg)
      Cf[cbase + (size_t)(row0 + rg) * 256 + col] = v4[rg];
  }
}

// ---- merged NS update (32-tile): z' = 0.25 z@t1 ; Y' = 0.25 Y@t1
// 1-D grid NBH*2*64 = 8192 blocks, bh-contiguous XCD swizzle.
__global__ __launch_bounds__(256) void ns_zy32(const bf16_t* __restrict__ zg,
    const bf16_t* __restrict__ Yg, const bf16_t* __restrict__ t1Tg,
    bf16_t* __restrict__ zog, bf16_t* __restrict__ Yog,
    bf16_t* __restrict__ YTog) {
  int bid = blockIdx.x;                       // 0..8191
  int orig = (bid & 7) * 1024 + (bid >> 3);   // XCD-contiguous remap
  int task = orig >> 6;                       // 0..127
  int bh = task >> 1;
  int which = task & 1;                       // 0: z-part, 1: Y-part
  int tile = orig & 63;
  int n0 = (tile & 7) << 5;
  int m0 = (tile >> 3) << 5;
  const bf16_t* A  = (which ? Yg : zg) + ((size_t)bh << 16);
  const bf16_t* BT = t1Tg + ((size_t)bh << 16);
  __shared__ short As[32][36];
  __shared__ short Bs[32][36];
  int tid = threadIdx.x;
  int lane = tid & 63;
  int wv = tid >> 6;
  int wm = (wv & 1) << 4, wn = (wv >> 1) << 4;
  int l15 = lane & 15, l16 = lane >> 4;
  f32x4 acc = (f32x4){0.f, 0.f, 0.f, 0.f};
  int ar0 = tid >> 3, ac0 = (tid & 7) << 2;
  const bf16_t* Ab = A + (size_t)(m0 + ar0) * 256 + ac0;
  const bf16_t* Bb = BT + (size_t)(n0 + ar0) * 256 + ac0;
  uint2 ga = *(const uint2*)Ab;
  uint2 gb = *(const uint2*)Bb;
  for (int k0 = 0; k0 < 256; k0 += 32) {
    *(uint2*)&As[ar0][ac0] = ga;
    *(uint2*)&Bs[ar0][ac0] = gb;
    __syncthreads();
    if (k0 + 32 < 256) {
      ga = *(const uint2*)(Ab + k0 + 32);
      gb = *(const uint2*)(Bb + k0 + 32);
    }
    bf16x8 af = *(const bf16x8*)&As[wm + l15][l16 * 8];
    bf16x8 bf = *(const bf16x8*)&Bs[wn + l15][l16 * 8];
    acc = __builtin_amdgcn_mfma_f32_16x16x32_bf16(af, bf, acc, 0, 0, 0);
    __syncthreads();
  }
  size_t cbase = (size_t)bh << 16;
  int row0 = m0 + wm + l16 * 4;
  int col = n0 + wn + l15;
  float v4[4];
#pragma unroll
  for (int rg = 0; rg < 4; ++rg) v4[rg] = 0.25f * acc[rg];
  if (which == 0) {
#pragma unroll
    for (int rg = 0; rg < 4; ++rg)
      zog[cbase + (size_t)(row0 + rg) * 256 + col] = f2bf(v4[rg]);
  } else {
#pragma unroll
    for (int rg = 0; rg < 4; ++rg)
      Yog[cbase + (size_t)(row0 + rg) * 256 + col] = f2bf(v4[rg]);
    ushort4 pk;
    pk.x = f2bf(v4[0]); pk.y = f2bf(v4[1]);
    pk.z = f2bf(v4[2]); pk.w = f2bf(v4[3]);
    *(ushort4*)(YTog + cbase + (size_t)col * 256 + row0) = pk;
  }
}

// ------------------------------------------------------------- landmark pool
__global__ __launch_bounds__(64) void pool_kernel(const bf16_t* __restrict__ q,
    const bf16_t* __restrict__ k, bf16_t* __restrict__ qlb,
    bf16_t* __restrict__ klb) {
  int bh = blockIdx.y, i = blockIdx.x, d = threadIdx.x;
  const bf16_t* qb = q + ((size_t)bh * SEQ + i * 16) * DH + d;
  const bf16_t* kb = k + ((size_t)bh * SEQ + i * 16) * DH + d;
  float sq = 0.f, sk = 0.f;
#pragma unroll
  for (int j = 0; j < 16; ++j) { sq += bf2f(qb[j * DH]); sk += bf2f(kb[j * DH]); }
  sq *= (1.f / 16.f); sk *= (1.f / 16.f);
  qlb[((size_t)bh * MLM + i) * DH + d] = f2bf(sq);
  klb[((size_t)bh * MLM + i) * DH + d] = f2bf(sk);
}

// ---------------------------------------------------- softmax rows of 256
__global__ __launch_bounds__(256) void softmax256(const float* __restrict__ af,
    bf16_t* __restrict__ ab) {
  const float* ar = af + (size_t)blockIdx.x * MLM;
  int t = threadIdx.x;
  float v = ar[t];
  __shared__ float redm[4], reds[4];
  float m = v;
#pragma unroll
  for (int off = 32; off > 0; off >>= 1) m = fmaxf(m, __shfl_xor(m, off));
  if ((t & 63) == 0) redm[t >> 6] = m;
  __syncthreads();
  m = fmaxf(fmaxf(redm[0], redm[1]), fmaxf(redm[2], redm[3]));
  float p = __expf(v - m);
  float s = p;
#pragma unroll
  for (int off = 32; off > 0; off >>= 1) s += __shfl_xor(s, off);
  if ((t & 63) == 0) reds[t >> 6] = s;
  __syncthreads();
  s = reds[0] + reds[1] + reds[2] + reds[3];
  ab[(size_t)blockIdx.x * MLM + t] = f2bf(p / s);
}

// ------------------------------------------- pinv scalars: global max sums
__global__ void init_scal(unsigned* s) { if (threadIdx.x < 2) s[threadIdx.x] = 0u; }

// grid (NBH, 2): task 0 = row sums -> scal[0] ("col"), task 1 = col sums ->
// scal[1] ("row"). Split halves the serial critical path vs the fused r16
// version; identical add order per sum -> identical scal bits.
__global__ __launch_bounds__(256) void colrow_max(const bf16_t* __restrict__ a,
    unsigned* __restrict__ scal) {
  int bh = blockIdx.x;
  int task = blockIdx.y;
  const bf16_t* ab = a + (size_t)bh * MLM * MLM;
  int t = threadIdx.x;
  float s = 0.f;
  if (task == 0) {
    const bf16_t* rp = ab + (size_t)t * MLM;
    for (int j = 0; j < MLM; j += 8) {
      float d[8];
      unp8(rp + j, d);
      s += d[0]; s += d[1]; s += d[2]; s += d[3];
      s += d[4]; s += d[5]; s += d[6]; s += d[7];
    }
  } else {
    for (int i = 0; i < MLM; ++i) s += bf2f(ab[(size_t)i * MLM + t]);
  }
  __shared__ float red[4];
  float m = s;
#pragma unroll
  for (int off = 32; off > 0; off >>= 1) m = fmaxf(m, __shfl_xor(m, off));
  if ((t & 63) == 0) red[t >> 6] = m;
  __syncthreads();
  if (t == 0) {
    m = fmaxf(fmaxf(red[0], red[1]), fmaxf(red[2], red[3]));
    atomicMax(scal + task, __float_as_uint(m));
  }
}

// z0 = a^T / denom (bf16), z0T = a / denom (bf16)
__global__ __launch_bounds__(256) void zinit(const bf16_t* __restrict__ ab,
    bf16_t* __restrict__ z0, bf16_t* __restrict__ z0T,
    const unsigned* __restrict__ scal) {
  size_t idx = (size_t)blockIdx.x * 256 + threadIdx.x;
  float denom = __uint_as_float(scal[0]) * __uint_as_float(scal[1]);
  size_t bh = idx >> 16;
  int i = (int)((idx >> 8) & 255);
  int j = (int)(idx & 255);
  bf16_t r = f2bf(bf2f(ab[idx]) / denom);
  z0T[idx] = r;
  z0[(bh << 16) + ((size_t)j << 8) + i] = r;
}

// --------- attn3v (MFMA flash): partial softmax(q_l@k^T)@v over 512-key chunk
__global__ __launch_bounds__(64) void attn3v_mfma(const bf16_t* __restrict__ qlb,
    const bf16_t* __restrict__ kg, const bf16_t* __restrict__ vT,
    float* __restrict__ pacc, float* __restrict__ pm, float* __restrict__ ps) {
  int bid = blockIdx.x;                       // 0..4095 (4096 % 8 == 0)
  int orig = (bid & 7) * 512 + (bid >> 3);    // XCD-contiguous remap
  int m0 = (orig & 7) << 5;                   // q-row tile
  int cz = (orig >> 3) & 7;                   // 512-key chunk
  int bh = orig >> 6;                         // batch*head
  int lane = threadIdx.x;
  int l15 = lane & 15, l16 = lane >> 4;
  __shared__ short plds[32][136];
  const bf16_t* qbase = qlb + (size_t)bh * MLM * DH;
  const bf16_t* kbase = kg + (size_t)bh * SEQ * DH;
  const bf16_t* vbase = vT + (size_t)bh * DH * SEQ;
  bf16x8 af[2][2];
#pragma unroll
  for (int mt = 0; mt < 2; ++mt)
#pragma unroll
    for (int ks = 0; ks < 2; ++ks)
      af[mt][ks] = *(const bf16x8*)(qbase + (size_t)(m0 + mt * 16 + l15) * DH + ks * 32 + l16 * 8);
  float m_run[2][4], s_run[2][4];
  f32x4 o[2][4];
#pragma unroll
  for (int mt = 0; mt < 2; ++mt) {
#pragma unroll
    for (int rg = 0; rg < 4; ++rg) { m_run[mt][rg] = -1e30f; s_run[mt][rg] = 0.f; }
#pragma unroll
    for (int n2 = 0; n2 < 4; ++n2) o[mt][n2] = (f32x4){0.f, 0.f, 0.f, 0.f};
  }
  int kbeg = cz << 9;
  for (int kt = kbeg; kt < kbeg + 512; kt += 128) {
    f32x4 sacc[2][8];
#pragma unroll
    for (int mt = 0; mt < 2; ++mt)
#pragma unroll
      for (int nt = 0; nt < 8; ++nt) sacc[mt][nt] = (f32x4){0.f, 0.f, 0.f, 0.f};
#pragma unroll
    for (int nt = 0; nt < 8; ++nt) {
      const bf16_t* kr = kbase + (size_t)(kt + nt * 16 + l15) * DH + l16 * 8;
      bf16x8 b0 = *(const bf16x8*)kr;
      bf16x8 b1 = *(const bf16x8*)(kr + 32);
      sacc[0][nt] = __builtin_amdgcn_mfma_f32_16x16x32_bf16(af[0][0], b0, sacc[0][nt], 0, 0, 0);
      sacc[0][nt] = __builtin_amdgcn_mfma_f32_16x16x32_bf16(af[0][1], b1, sacc[0][nt], 0, 0, 0);
      sacc[1][nt] = __builtin_amdgcn_mfma_f32_16x16x32_bf16(af[1][0], b0, sacc[1][nt], 0, 0, 0);
      sacc[1][nt] = __builtin_amdgcn_mfma_f32_16x16x32_bf16(af[1][1], b1, sacc[1][nt], 0, 0, 0);
    }
#pragma unroll
    for (int mt = 0; mt < 2; ++mt)
#pragma unroll
      for (int rg = 0; rg < 4; ++rg) {
        float mx = sacc[mt][0][rg];
#pragma unroll
        for (int nt = 1; nt < 8; ++nt) mx = fmaxf(mx, sacc[mt][nt][rg]);
        mx = fmaxf(mx, __shfl_xor(mx, 1));
        mx = fmaxf(mx, __shfl_xor(mx, 2));
        mx = fmaxf(mx, __shfl_xor(mx, 4));
        mx = fmaxf(mx, __shfl_xor(mx, 8));
        float mnew = fmaxf(m_run[mt][rg], mx);
        float corr = __expf(m_run[mt][rg] - mnew);
        float s = 0.f;
#pragma unroll
        for (int nt = 0; nt < 8; ++nt) {
          float p = __expf(sacc[mt][nt][rg] - mnew);
          sacc[mt][nt][rg] = p;
          s += p;
        }
        s += __shfl_xor(s, 1); s += __shfl_xor(s, 2);
        s += __shfl_xor(s, 4); s += __shfl_xor(s, 8);
        s_run[mt][rg] = s_run[mt][rg] * corr + s;
        m_run[mt][rg] = mnew;
#pragma unroll
        for (int n2 = 0; n2 < 4; ++n2) o[mt][n2][rg] *= corr;
      }
#pragma unroll
    for (int mt = 0; mt < 2; ++mt)
#pragma unroll
      for (int nt = 0; nt < 8; ++nt)
#pragma unroll
        for (int rg = 0; rg < 4; ++rg)
          plds[mt * 16 + l16 * 4 + rg][nt * 16 + l15] = (short)f2bf(sacc[mt][nt][rg]);
#pragma unroll
    for (int ks2 = 0; ks2 < 4; ++ks2) {
      bf16x8 pa0 = *(const bf16x8*)&plds[l15][ks2 * 32 + l16 * 8];
      bf16x8 pa1 = *(const bf16x8*)&plds[16 + l15][ks2 * 32 + l16 * 8];
#pragma unroll
      for (int n2 = 0; n2 < 4; ++n2) {
        bf16x8 vb8 = *(const bf16x8*)(vbase + (size_t)(n2 * 16 + l15) * SEQ + kt + ks2 * 32 + l16 * 8);
        o[0][n2] = __builtin_amdgcn_mfma_f32_16x16x32_bf16(pa0, vb8, o[0][n2], 0, 0, 0);
        o[1][n2] = __builtin_amdgcn_mfma_f32_16x16x32_bf16(pa1, vb8, o[1][n2], 0, 0, 0);
      }
    }
  }
  size_t pidx0 = (size_t)(bh * 8 + cz) * MLM + m0;
#pragma unroll
  for (int mt = 0; mt < 2; ++mt)
#pragma unroll
    for (int n2 = 0; n2 < 4; ++n2)
#pragma unroll
      for (int rg = 0; rg < 4; ++rg) {
        int row = mt * 16 + l16 * 4 + rg;
        pacc[(pidx0 + row) * 64 + n2 * 16 + l15] = o[mt][n2][rg];
      }
  if (l15 == 0) {
#pragma unroll
    for (int mt = 0; mt < 2; ++mt)
#pragma unroll
      for (int rg = 0; rg < 4; ++rg) {
        pm[pidx0 + mt * 16 + l16 * 4 + rg] = m_run[mt][rg];
        ps[pidx0 + mt * 16 + l16 * 4 + rg] = s_run[mt][rg];
      }
  }
}

// --------------- attn3v phase 2: combine 8 chunk-partials -> a3v bf16
__global__ __launch_bounds__(256) void attn3v_comb(const float* __restrict__ pacc,
    const float* __restrict__ pm, const float* __restrict__ ps,
    bf16_t* __restrict__ a3vb) {
  int gw = blockIdx.x * 4 + (threadIdx.x >> 6);  // row id 0..16383
  int lane = threadIdx.x & 63;
  int bh = gw >> 8, row = gw & 255;
  float ms[8];
  float M = -1e30f;
#pragma unroll
  for (int cc = 0; cc < 8; ++cc) {
    ms[cc] = pm[(size_t)(bh * 8 + cc) * MLM + row];
    M = fmaxf(M, ms[cc]);
  }
  float S = 0.f, val = 0.f;
#pragma unroll
  for (int cc = 0; cc < 8; ++cc) {
    size_t pidx = (size_t)(bh * 8 + cc) * MLM + row;
    float w = __expf(ms[cc] - M);
    S += w * ps[pidx];
    val += w * pacc[pidx * 64 + lane];
  }
  a3vb[(size_t)gw * 64 + lane] = f2bf(val / S);
}

// ---------------- wm^T = (zc @ a3v)^T  bf16 [bh][64][256]
__global__ __launch_bounds__(256) void wm_kernel(const bf16_t* __restrict__ zb,
    const bf16_t* __restrict__ a3vb, bf16_t* __restrict__ wmT) {
  int bh = blockIdx.y;
  int m0 = blockIdx.x << 6;
  __shared__ bf16_t a3s[MLM * DH];
  int t = threadIdx.x;
  const bf16_t* asrc = a3vb + (size_t)bh * MLM * DH;
#pragma unroll
  for (int i = 0; i < 8; ++i)
    *(bf16x8*)(a3s + ((size_t)t + 256 * i) * 8) =
        *(const bf16x8*)(asrc + ((size_t)t + 256 * i) * 8);
  __syncthreads();
  int row = m0 + (t >> 2);
  int c0 = (t & 3) * 16;
  const bf16_t* zrow = zb + (size_t)bh * 65536 + (size_t)row * 256;
  float acc16[16] = {};
  for (int k0 = 0; k0 < 256; k0 += 8) {
    float a8[8];
    unp8(zrow + k0, a8);
#pragma unroll
    for (int j = 0; j < 8; ++j) {
      float av[16];
      unp8(a3s + (k0 + j) * 64 + c0, av);
      unp8(a3s + (k0 + j) * 64 + c0 + 8, av + 8);
#pragma unroll
      for (int e = 0; e < 16; ++e) acc16[e] += a8[j] * av[e];
    }
  }
  bf16_t* wd = wmT + (size_t)bh * DH * MLM;
#pragma unroll
  for (int e = 0; e < 16; ++e)
    wd[(size_t)(c0 + e) * MLM + row] = f2bf(acc16[e]);
}

// ---------- attn1 (MFMA): om = softmax(q @ k_l^T) @ W, one wave = 32 q-rows
__global__ __launch_bounds__(64) void attn1_mfma(const bf16_t* __restrict__ qg,
    const bf16_t* __restrict__ klb, const bf16_t* __restrict__ wmT,
    bf16_t* __restrict__ om) {
  int bh = blockIdx.y, bat = bh >> 3, head = bh & 7;
  int m0 = blockIdx.x << 5;
  int lane = threadIdx.x;
  int l15 = lane & 15, l16 = lane >> 4;
  __shared__ short plds[32][264];
  const bf16_t* qbase = qg + (size_t)bh * SEQ * DH;
  const bf16_t* kbase = klb + (size_t)bh * MLM * DH;
  bf16x8 af[2][2];
#pragma unroll
  for (int mt = 0; mt < 2; ++mt)
#pragma unroll
    for (int ks = 0; ks < 2; ++ks)
      af[mt][ks] = *(const bf16x8*)(qbase + (size_t)(m0 + mt * 16 + l15) * DH + ks * 32 + l16 * 8);
  f32x4 acc[2][16];
#pragma unroll
  for (int mt = 0; mt < 2; ++mt)
#pragma unroll
    for (int nt = 0; nt < 16; ++nt) acc[mt][nt] = (f32x4){0.f, 0.f, 0.f, 0.f};
#pragma unroll
  for (int nt = 0; nt < 16; ++nt) {
    bf16x8 b0 = *(const bf16x8*)(kbase + (size_t)(nt * 16 + l15) * DH + l16 * 8);
    bf16x8 b1 = *(const bf16x8*)(kbase + (size_t)(nt * 16 + l15) * DH + 32 + l16 * 8);
    acc[0][nt] = __builtin_amdgcn_mfma_f32_16x16x32_bf16(af[0][0], b0, acc[0][nt], 0, 0, 0);
    acc[0][nt] = __builtin_amdgcn_mfma_f32_16x16x32_bf16(af[0][1], b1, acc[0][nt], 0, 0, 0);
    acc[1][nt] = __builtin_amdgcn_mfma_f32_16x16x32_bf16(af[1][0], b0, acc[1][nt], 0, 0, 0);
    acc[1][nt] = __builtin_amdgcn_mfma_f32_16x16x32_bf16(af[1][1], b1, acc[1][nt], 0, 0, 0);
  }
  float inv[2][4];
#pragma unroll
  for (int mt = 0; mt < 2; ++mt)
#pragma unroll
    for (int rg = 0; rg < 4; ++rg) {
      float mx = acc[mt][0][rg];
#pragma unroll
      for (int nt = 1; nt < 16; ++nt) mx = fmaxf(mx, acc[mt][nt][rg]);
      mx = fmaxf(mx, __shfl_xor(mx, 1));
      mx = fmaxf(mx, __shfl_xor(mx, 2));
      mx = fmaxf(mx, __shfl_xor(mx, 4));
      mx = fmaxf(mx, __shfl_xor(mx, 8));
      float s = 0.f;
#pragma unroll
      for (int nt = 0; nt < 16; ++nt) {
        float p = __expf(acc[mt][nt][rg] - mx);
        acc[mt][nt][rg] = p;
        s += p;
      }
      s += __shfl_xor(s, 1); s += __shfl_xor(s, 2);
      s += __shfl_xor(s, 4); s += __shfl_xor(s, 8);
      inv[mt][rg] = 1.f / s;
    }
#pragma unroll
  for (int mt = 0; mt < 2; ++mt)
#pragma unroll
    for (int nt = 0; nt < 16; ++nt)
#pragma unroll
      for (int rg = 0; rg < 4; ++rg)
        plds[mt * 16 + l16 * 4 + rg][nt * 16 + l15] = (short)f2bf(acc[mt][nt][rg]);
  const bf16_t* wbase = wmT + (size_t)bh * DH * MLM;
  f32x4 o[2][4];
#pragma unroll
  for (int mt = 0; mt < 2; ++mt)
#pragma unroll
    for (int n2 = 0; n2 < 4; ++n2) o[mt][n2] = (f32x4){0.f, 0.f, 0.f, 0.f};
#pragma unroll
  for (int ks = 0; ks < 8; ++ks) {
    bf16x8 pa0 = *(const bf16x8*)&plds[l15][ks * 32 + l16 * 8];
    bf16x8 pa1 = *(const bf16x8*)&plds[16 + l15][ks * 32 + l16 * 8];
#pragma unroll
    for (int n2 = 0; n2 < 4; ++n2) {
      bf16x8 wb = *(const bf16x8*)(wbase + (size_t)(n2 * 16 + l15) * MLM + ks * 32 + l16 * 8);
      o[0][n2] = __builtin_amdgcn_mfma_f32_16x16x32_bf16(pa0, wb, o[0][n2], 0, 0, 0);
      o[1][n2] = __builtin_amdgcn_mfma_f32_16x16x32_bf16(pa1, wb, o[1][n2], 0, 0, 0);
    }
  }
#pragma unroll
  for (int mt = 0; mt < 2; ++mt)
#pragma unroll
    for (int n2 = 0; n2 < 4; ++n2)
#pragma unroll
      for (int rg = 0; rg < 4; ++rg) {
        int n = m0 + mt * 16 + l16 * 4 + rg;
        int d = n2 * 16 + l15;
        om[((size_t)(bat * SEQ + n)) * DMODEL + head * DH + d] =
            f2bf(o[mt][n2][rg] * inv[mt][rg]);
      }
}

// --------------------- depthwise conv(v) added into om (bf16 RMW)
__global__ __launch_bounds__(256) void conv_add(const bf16_t* __restrict__ vg,
    const float* __restrict__ rk, bf16_t* __restrict__ om) {
  int bh = blockIdx.y, bat = bh >> 3, head = bh & 7;
  int n0 = blockIdx.x << 5;
  __shared__ bf16_t vs[64 * 64];
  int t = threadIdx.x;
  const bf16_t* vbase = vg + (size_t)bh * SEQ * DH;
#pragma unroll
  for (int i = 0; i < 2; ++i) {
    int li = t + 256 * i;
    int rr = li >> 3, cc = (li & 7) << 3;
    int src = n0 - 16 + rr;
    bf16x8 val;
    if (src >= 0 && src < SEQ) val = *(const bf16x8*)(vbase + (size_t)src * DH + cc);
    else { short z = 0; val = (bf16x8){z, z, z, z, z, z, z, z}; }
    *(bf16x8*)(vs + rr * 64 + cc) = val;
  }
  __syncthreads();
  float w[33];
#pragma unroll
  for (int i = 0; i < 33; ++i) w[i] = rk[head * 33 + i];
  int d = t & 63;
  int r0 = (t >> 6) << 3;
  float out[8] = {0.f, 0.f, 0.f, 0.f, 0.f, 0.f, 0.f, 0.f};
#pragma unroll
  for (int j = 0; j < 40; ++j) {
    float vv = bf2f(vs[(r0 + j) * 64 + d]);
    int ilo = j - 32; if (ilo < 0) ilo = 0;
    int ihi = j; if (ihi > 7) ihi = 7;
    for (int i = ilo; i <= ihi; ++i) out[i] += w[j - i] * vv;
  }
#pragma unroll
  for (int i = 0; i < 8; ++i) {
    int n = n0 + r0 + i;
    size_t idx = ((size_t)(bat * SEQ + n)) * DMODEL + head * DH + d;
    om[idx] = f2bf(bf2f(om[idx]) + out[i]);
  }
}

// ---------------------------------------------------------------- launcher
extern "C" void kernel_launch(void* const* d_in, const int* in_sizes, int n_in,
                              void* d_out, int out_size, void* d_ws, size_t ws_size,
                              hipStream_t stream) {
  const float* x     = (const float*)d_in[0];
  const float* gamma = (const float*)d_in[1];
  const float* beta  = (const float*)d_in[2];
  const float* w_qkv = (const float*)d_in[3];
  const float* w_out = (const float*)d_in[4];
  const float* b_out = (const float*)d_in[5];
  const float* rk    = (const float*)d_in[6];
  float* y  = (float*)d_out;

  // ---- workspace layout (221.3 MB total) ----
  bf16_t* xnb  = (bf16_t*)d_ws;           // 16777216 (reused as om)
  bf16_t* qb   = xnb + 16777216;
  bf16_t* kb   = qb + 16777216;
  bf16_t* vb   = kb + 16777216;
  bf16_t* wqkvT = vb + 16777216;          // 786432
  bf16_t* woutT = wqkvT + 786432;         // 262144
  bf16_t* qlb  = woutT + 262144;          // 1048576
  bf16_t* klb  = qlb + 1048576;           // 1048576
  bf16_t* a2b  = klb + 1048576;           // 4194304
  // NS slots (4 x 4194304): zA/zB (z ping-pong), Ya/Yb (Y ping-pong)
  bf16_t* zA   = a2b + 4194304;
  bf16_t* z0T  = zA + 4194304;            // z0T for Y0 GEMM; then reused as Yb
  bf16_t* zB   = z0T + 4194304;
  bf16_t* Ya   = zB + 4194304;
  bf16_t* Yb   = z0T;                     // alias (z0T dead after Y0 GEMM)
  bf16_t* vTb  = zA;                      // alias: vT [bh][64][4096] (dead before zinit)
  bf16_t* a3vb = Ya + 4194304;            // 1048576
  bf16_t* wmT  = a3vb + 1048576;          // 1048576
  // shared region SR (33.55 MB): a2f32 -> pacc -> {YTa, YTb, t2T, t1T}
  float*  SR   = (float*)(wmT + 1048576); // 8388608 f32
  float*  a2f  = SR;
  float*  pacc = SR;
  bf16_t* YTa  = (bf16_t*)SR;
  bf16_t* YTb  = YTa + 4194304;
  bf16_t* t2T  = YTa + 8388608;
  bf16_t* t1T  = YTa + 12582912;
  float*  pm   = SR + 8388608;            // 131072
  float*  ps   = pm + 131072;             // 131072
  unsigned* scal = (unsigned*)(ps + 131072);
  size_t need = (size_t)93323264 * 2 + (size_t)(8388608 + 262144) * 4 + 64;
  if (ws_size < need) return;  // clean fail instead of OOB fault

  ln_kernel<<<NROWS, 64, 0, stream>>>(x, gamma, beta, xnb);
  convT<<<3072, 256, 0, stream>>>(w_qkv, wqkvT, 512, 1536);
  convT<<<1024, 256, 0, stream>>>(w_out, woutT, 512, 512);

  gemm_qkv_mfma<<<3072, 256, 0, stream>>>(xnb, wqkvT, qb, kb, vb, vTb);
  pool_kernel<<<dim3(MLM, NBH), 64, 0, stream>>>(qb, kb, qlb, klb);

  // sim2 = q_l @ k_l^T (32-tile MFMA, f32 out), softmax -> a2b bf16
  bmm_mfma32<<<4096, 256, 0, stream>>>(qlb, klb, nullptr, nullptr, a2f,
      64, 1.f, 0.f, 0.f, 4);
  softmax256<<<NBH * MLM, 256, 0, stream>>>(a2f, a2b);

  init_scal<<<1, 64, 0, stream>>>(scal);
  colrow_max<<<dim3(NBH, 2), 256, 0, stream>>>(a2b, scal);

  // attn3v split-K MFMA flash, XCD-swizzled (vT aliases NS region; dead after)
  attn3v_mfma<<<4096, 64, 0, stream>>>(qlb, kb, vTb, pacc, pm, ps);
  attn3v_comb<<<4096, 256, 0, stream>>>(pacc, pm, ps, a3vb);

  // pinv via Y-tracking chain, 32-tile GEMMs (4096-8192 blocks per dispatch;
  // r16's 64-tile at 1024 blocks was still latency-bound at ~12us/dispatch)
  zinit<<<16384, 256, 0, stream>>>(a2b, zA, z0T, scal);
  // Y0 = a2 @ z0  (= a2@a2^T/c): A=a2, BT=z0T -> Ya + YTa
  bmm_mfma32<<<4096, 256, 0, stream>>>(a2b, z0T, Ya, YTa, nullptr,
      256, 1.f, 0.f, 0.f, 3);
  bf16_t* zc = zA;  bf16_t* zo = zB;
  bf16_t* Yc = Ya;  bf16_t* YTc = YTa;
  bf16_t* Yo = Yb;  bf16_t* YTo = YTb;
  for (int it = 0; it < 6; ++it) {
    // t2 = Y@Y - 7Y + 15I  -> t2T
    bmm_mfma32<<<4096, 256, 0, stream>>>(Yc, YTc, nullptr, t2T, nullptr,
        256, 1.f, -7.f, 15.f, 2);
    // t1 = 13I - Y@t2      -> t1T
    bmm_mfma32<<<4096, 256, 0, stream>>>(Yc, t2T, nullptr, t1T, nullptr,
        256, -1.f, 0.f, 13.f, 2);
    // z' = 0.25 z@t1 ; Y' = 0.25 Y@t1 (merged, 8192 blocks)
    ns_zy32<<<8192, 256, 0, stream>>>(zc, Yc, t1T, zo, Yo, YTo);
    bf16_t* tp;
    tp = zc; zc = zo; zo = tp;
    tp = Yc; Yc = Yo; Yo = tp;
    tp = YTc; YTc = YTo; YTo = tp;
  }
  // zc == zA after even number of swaps

  // wm^T = (z6 @ a3v)^T
  wm_kernel<<<dim3(4, NBH), 256, 0, stream>>>(zc, a3vb, wmT);

  // attn1 (MFMA) -> om, then depthwise conv added
  bf16_t* om = xnb;
  attn1_mfma<<<dim3(SEQ / 32, NBH), 64, 0, stream>>>(qb, klb, wmT, om);
  conv_add<<<dim3(SEQ / 32, NBH), 256, 0, stream>>>(vb, rk, om);

  // y = x + om @ w_out + b_out
  gemm_out_mfma<<<1024, 256, 0, stream>>>(om, woutT, b_out, x, y);
}

// Round 2
// 766.856 us; speedup vs baseline: 1.0053x; 1.0053x over previous
//
#include <hip/hip_runtime.h>

#define SEQ 4096
#define DMODEL 512
#define NH 8
#define DH 64
#define MLM 256
#define NBH 64          // B*H = 8*8
#define NROWS 32768     // B*SEQ

typedef unsigned short bf16_t;
typedef __attribute__((ext_vector_type(8))) short bf16x8;
typedef __attribute__((ext_vector_type(4))) float f32x4;

__device__ __forceinline__ float bf2f(unsigned short u) {
  return __uint_as_float(((unsigned)u) << 16);
}
__device__ __forceinline__ unsigned short f2bf(float f) {
  unsigned u = __float_as_uint(f);
  u += 0x7fffu + ((u >> 16) & 1u);
  return (unsigned short)(u >> 16);
}
// unpack 8 consecutive bf16 at p into d[0..7]
__device__ __forceinline__ void unp8(const bf16_t* p, float* d) {
  uint4 u = *(const uint4*)p;
  d[0] = __uint_as_float(u.x << 16); d[1] = __uint_as_float(u.x & 0xffff0000u);
  d[2] = __uint_as_float(u.y << 16); d[3] = __uint_as_float(u.y & 0xffff0000u);
  d[4] = __uint_as_float(u.z << 16); d[5] = __uint_as_float(u.z & 0xffff0000u);
  d[6] = __uint_as_float(u.w << 16); d[7] = __uint_as_float(u.w & 0xffff0000u);
}

// async global->LDS, 16B per lane, wave-uniform LDS base + lane*16 (m104)
__device__ __forceinline__ void gll(const void* g, void* l) {
  __builtin_amdgcn_global_load_lds(
      (const __attribute__((address_space(1))) unsigned int*)g,
      (__attribute__((address_space(3))) unsigned int*)l, 16, 0, 0);
}

// ---------------------------------------------------------------- LayerNorm
__global__ __launch_bounds__(64) void ln_kernel(const float* __restrict__ x,
    const float* __restrict__ gamma, const float* __restrict__ beta,
    bf16_t* __restrict__ xn) {
  int row = blockIdx.x;
  const float4* xr = (const float4*)(x + (size_t)row * DMODEL);
  int t = threadIdx.x;
  float4 a = xr[t], b = xr[t + 64];
  float s  = a.x + a.y + a.z + a.w + b.x + b.y + b.z + b.w;
  float ss = a.x*a.x + a.y*a.y + a.z*a.z + a.w*a.w
           + b.x*b.x + b.y*b.y + b.z*b.z + b.w*b.w;
#pragma unroll
  for (int off = 32; off > 0; off >>= 1) {
    s  += __shfl_xor(s, off);
    ss += __shfl_xor(ss, off);
  }
  float mean = s * (1.0f / DMODEL);
  float var  = ss * (1.0f / DMODEL) - mean * mean;
  float rstd = rsqrtf(var + 1e-5f);
  const float4* g4 = (const float4*)gamma;
  const float4* be4 = (const float4*)beta;
  ushort4* o = (ushort4*)(xn + (size_t)row * DMODEL);
  float4 g = g4[t], bb = be4[t];
  ushort4 r;
  r.x = f2bf((a.x - mean) * rstd * g.x + bb.x);
  r.y = f2bf((a.y - mean) * rstd * g.y + bb.y);
  r.z = f2bf((a.z - mean) * rstd * g.z + bb.z);
  r.w = f2bf((a.w - mean) * rstd * g.w + bb.w);
  o[t] = r;
  g = g4[t + 64]; bb = be4[t + 64];
  r.x = f2bf((b.x - mean) * rstd * g.x + bb.x);
  r.y = f2bf((b.y - mean) * rstd * g.y + bb.y);
  r.z = f2bf((b.z - mean) * rstd * g.z + bb.z);
  r.w = f2bf((b.w - mean) * rstd * g.w + bb.w);
  o[t + 64] = r;
}

// ------------------------------------- weight convert + transpose (fp32->bf16)
__global__ __launch_bounds__(256) void convT(const float* __restrict__ w,
    bf16_t* __restrict__ wt, int K, int N) {
  size_t idx = (size_t)blockIdx.x * 256 + threadIdx.x;
  int n = (int)(idx / K), k = (int)(idx % K);
  wt[idx] = f2bf(w[(size_t)k * N + n]);
}

// ----------------------- MFMA 128x128 tile GEMM body (A, BT bf16 row-major-K)
// global_load_lds width-16 staging, unpadded [128][32] LDS (wave-linear dest).
#define MFMA_GEMM_BODY(APTR, BTPTR, KDIM) \
  __shared__ short As[128][32]; \
  __shared__ short Bs[128][32]; \
  int tid = threadIdx.x; \
  int lane = tid & 63; \
  int wv = tid >> 6; \
  int wm = (wv & 1) << 6, wn = (wv >> 1) << 6; \
  int l15 = lane & 15, l16 = lane >> 4; \
  f32x4 acc[4][4]; \
  _Pragma("unroll") for (int fm = 0; fm < 4; ++fm) \
    _Pragma("unroll") for (int fn = 0; fn < 4; ++fn) \
      acc[fm][fn] = (f32x4){0.f, 0.f, 0.f, 0.f}; \
  int ar0 = tid >> 2, ac0 = (tid & 3) << 3; \
  const bf16_t* Ab  = (APTR) + (size_t)(m0 + ar0) * (KDIM) + ac0; \
  const bf16_t* Ab1 = (APTR) + (size_t)(m0 + ar0 + 64) * (KDIM) + ac0; \
  const bf16_t* Bb  = (BTPTR) + (size_t)(n0 + ar0) * (KDIM) + ac0; \
  const bf16_t* Bb1 = (BTPTR) + (size_t)(n0 + ar0 + 64) * (KDIM) + ac0; \
  short* AsW  = &As[(wv << 4)][0]; \
  short* AsW1 = &As[64 + (wv << 4)][0]; \
  short* BsW  = &Bs[(wv << 4)][0]; \
  short* BsW1 = &Bs[64 + (wv << 4)][0]; \
  for (int k0 = 0; k0 < (KDIM); k0 += 32) { \
    gll(Ab + k0, AsW);  gll(Ab1 + k0, AsW1); \
    gll(Bb + k0, BsW);  gll(Bb1 + k0, BsW1); \
    __syncthreads(); \
    bf16x8 af[4], bfr[4]; \
    _Pragma("unroll") for (int f = 0; f < 4; ++f) { \
      af[f]  = *(const bf16x8*)&As[wm + f * 16 + l15][l16 * 8]; \
      bfr[f] = *(const bf16x8*)&Bs[wn + f * 16 + l15][l16 * 8]; \
    } \
    _Pragma("unroll") for (int fm = 0; fm < 4; ++fm) \
      _Pragma("unroll") for (int fn = 0; fn < 4; ++fn) \
        acc[fm][fn] = __builtin_amdgcn_mfma_f32_16x16x32_bf16(af[fm], bfr[fn], acc[fm][fn], 0, 0, 0); \
    __syncthreads(); \
  }

// ======================= QKV projection: 256x256 tile, BK=32, 8 waves,
// 4-slot LDS ring + counted vmcnt pipeline (T3+T4), k-slot XOR swizzle (T2),
// setprio around MFMA cluster (T5). One s_barrier per K-tile.
// Numerics: same ascending 16-step K=32 MFMA chain per output as the 128^2
// body -> bit-identical to previous rounds.
__global__ __launch_bounds__(512) void gemm_qkv_256(const bf16_t* __restrict__ A,
    const bf16_t* __restrict__ BT, bf16_t* __restrict__ q, bf16_t* __restrict__ k,
    bf16_t* __restrict__ v, bf16_t* __restrict__ vT) {
  int bid = blockIdx.x;                        // 0..767 (768 % 8 == 0)
  int orig = (bid & 7) * 96 + (bid >> 3);      // XCD-contiguous remap
  int n0 = (orig % 6) << 8;
  int m0 = (orig / 6) << 8;
  __shared__ short As[4][8192];                // 4 slots x [256 rows][32 k]
  __shared__ short Bs[4][8192];                // 128 KiB total
  int tid = threadIdx.x;
  int lane = tid & 63;
  int wid = tid >> 6;                          // 0..7
  int wr = wid >> 2, wc = wid & 3;             // 2M x 4N wave grid
  int l15 = lane & 15, l16 = lane >> 4;
  // T2 swizzle: LDS[row][slot] holds global k-slot (slot ^ (row&3)).
  // Read side: want global slot l16 at row (..+l15) -> slot l16^(l15&3).
  int sl = (l16 ^ (l15 & 3)) << 3;             // element offset in row
  // Stage side (linear DMA dest): lane covers row +(lane>>2), slot (lane&3);
  // fetch global slot (lane&3)^(row&3) so content matches the mapping above.
  int gr  = lane >> 2;
  int gcs = ((lane & 3) ^ ((lane >> 2) & 3)) << 3;
  f32x4 acc[8][4];
#pragma unroll
  for (int fm = 0; fm < 8; ++fm)
#pragma unroll
    for (int fn = 0; fn < 4; ++fn) acc[fm][fn] = (f32x4){0.f, 0.f, 0.f, 0.f};

#define STAGE(kt, s) { \
    _Pragma("unroll") for (int u = 0; u < 2; ++u) { \
      int r0 = (wid << 5) + (u << 4); \
      gll(A  + (size_t)(m0 + r0 + gr) * 512 + (kt) * 32 + gcs, &As[s][r0 << 5]); \
      gll(BT + (size_t)(n0 + r0 + gr) * 512 + (kt) * 32 + gcs, &Bs[s][r0 << 5]); \
    } }

  STAGE(0, 0) STAGE(1, 1) STAGE(2, 2)          // 12 loads in flight
  for (int t = 0; t < 16; ++t) {
    int s = t & 3;
    // wait own loads for tile t (oldest); keep later tiles in flight
    if (t < 14)       asm volatile("s_waitcnt vmcnt(8)" ::: "memory");
    else if (t == 14) asm volatile("s_waitcnt vmcnt(4)" ::: "memory");
    else              asm volatile("s_waitcnt vmcnt(0)" ::: "memory");
    __builtin_amdgcn_s_barrier();              // all waves: tile t in LDS;
                                               // also: everyone drained reads
                                               // of slot (t-1)&3 last iter
    if (t + 3 < 16) STAGE(t + 3, ((t + 3) & 3))
    bf16x8 a[8], b[4];
#pragma unroll
    for (int fm = 0; fm < 8; ++fm)
      a[fm] = *(const bf16x8*)&As[s][(((wr << 7) + (fm << 4) + l15) << 5) + sl];
#pragma unroll
    for (int fn = 0; fn < 4; ++fn)
      b[fn] = *(const bf16x8*)&Bs[s][(((wc << 6) + (fn << 4) + l15) << 5) + sl];
    asm volatile("s_waitcnt lgkmcnt(0)" ::: "memory");  // reads drained before
    __builtin_amdgcn_sched_barrier(0);                  // next barrier (rule 18)
    __builtin_amdgcn_s_setprio(1);
#pragma unroll
    for (int fm = 0; fm < 8; ++fm)
#pragma unroll
      for (int fn = 0; fn < 4; ++fn)
        acc[fm][fn] = __builtin_amdgcn_mfma_f32_16x16x32_bf16(a[fm], b[fn], acc[fm][fn], 0, 0, 0);
    __builtin_amdgcn_s_setprio(0);
  }
#undef STAGE
  // ---- epilogue: identical per-element mapping to the 128^2 version
#pragma unroll
  for (int fm = 0; fm < 8; ++fm) {
    int row0 = m0 + (wr << 7) + (fm << 4) + (l16 << 2);
    int bat = row0 >> 12;
    int nn0 = row0 & 4095;
#pragma unroll
    for (int fn = 0; fn < 4; ++fn) {
      int col = n0 + (wc << 6) + (fn << 4) + l15;
      int which = col >> 9;
      int hd = (col >> 6) & 7;
      int d  = col & 63;
      if (which == 2) {
        ushort4 pk;
        pk.x = f2bf(acc[fm][fn][0]); pk.y = f2bf(acc[fm][fn][1]);
        pk.z = f2bf(acc[fm][fn][2]); pk.w = f2bf(acc[fm][fn][3]);
        *(ushort4*)(vT + ((size_t)(bat * NH + hd) * DH + d) * SEQ + nn0) = pk;
#pragma unroll
        for (int rg = 0; rg < 4; ++rg)
          v[(((size_t)(bat * NH + hd)) * SEQ + nn0 + rg) * DH + d] = f2bf(acc[fm][fn][rg]);
      } else {
        bf16_t* dst = (which == 0) ? q : k;
        float scale = (which == 0) ? 0.125f : 1.f;
#pragma unroll
        for (int rg = 0; rg < 4; ++rg)
          dst[(((size_t)(bat * NH + hd)) * SEQ + nn0 + rg) * DH + d] = f2bf(acc[fm][fn][rg] * scale);
      }
    }
  }
}

// Output projection (MFMA), XCD-swizzled: y = x + om(bf16) @ woutT^T + b_out
__global__ __launch_bounds__(256) void gemm_out_mfma(const bf16_t* __restrict__ A,
    const bf16_t* __restrict__ BT, const float* __restrict__ bias,
    const float* __restrict__ x, float* __restrict__ y) {
  int bid = blockIdx.x;                        // 0..1023
  int orig = (bid & 7) * 128 + (bid >> 3);     // XCD-contiguous remap
  int n0 = (orig & 3) << 7;
  int m0 = (orig >> 2) << 7;
  MFMA_GEMM_BODY(A, BT, 512)
#pragma unroll
  for (int fm = 0; fm < 4; ++fm) {
#pragma unroll
    for (int fn = 0; fn < 4; ++fn) {
      int col = n0 + wn + fn * 16 + l15;
      float bv = bias[col];
#pragma unroll
      for (int rg = 0; rg < 4; ++rg) {
        int row = m0 + wm + fm * 16 + l16 * 4 + rg;
        y[(size_t)row * DMODEL + col] = x[(size_t)row * DMODEL + col] + acc[fm][fn][rg] + bv;
      }
    }
  }
}

// ---- 32x32-tile batched MFMA GEMM over 256x256 matrices.
__global__ __launch_bounds__(256) void bmm_mfma32(const bf16_t* __restrict__ Ag,
    const bf16_t* __restrict__ BTg, bf16_t* __restrict__ Cb,
    bf16_t* __restrict__ CTb, float* __restrict__ Cf,
    int K, float alpha, float eA, float diagc, int flags) {
  int bid = blockIdx.x;                       // 0..4095
  int orig = (bid & 7) * 512 + (bid >> 3);    // XCD-contiguous remap
  int bh = orig >> 6;
  int tile = orig & 63;
  int n0 = (tile & 7) << 5;
  int m0 = (tile >> 3) << 5;
  const bf16_t* A  = Ag + (size_t)bh * 256 * K;
  const bf16_t* BT = BTg + (size_t)bh * 256 * K;
  __shared__ short As[32][36];
  __shared__ short Bs[32][36];
  int tid = threadIdx.x;
  int lane = tid & 63;
  int wv = tid >> 6;
  int wm = (wv & 1) << 4, wn = (wv >> 1) << 4;
  int l15 = lane & 15, l16 = lane >> 4;
  f32x4 acc = (f32x4){0.f, 0.f, 0.f, 0.f};
  int ar0 = tid >> 3, ac0 = (tid & 7) << 2;
  const bf16_t* Ab = A + (size_t)(m0 + ar0) * K + ac0;
  const bf16_t* Bb = BT + (size_t)(n0 + ar0) * K + ac0;
  uint2 ga = *(const uint2*)Ab;
  uint2 gb = *(const uint2*)Bb;
  for (int k0 = 0; k0 < K; k0 += 32) {
    *(uint2*)&As[ar0][ac0] = ga;
    *(uint2*)&Bs[ar0][ac0] = gb;
    __syncthreads();
    if (k0 + 32 < K) {
      ga = *(const uint2*)(Ab + k0 + 32);
      gb = *(const uint2*)(Bb + k0 + 32);
    }
    bf16x8 af = *(const bf16x8*)&As[wm + l15][l16 * 8];
    bf16x8 bf = *(const bf16x8*)&Bs[wn + l15][l16 * 8];
    acc = __builtin_amdgcn_mfma_f32_16x16x32_bf16(af, bf, acc, 0, 0, 0);
    __syncthreads();
  }
  size_t cbase = (size_t)bh * 65536;
  int row0 = m0 + wm + l16 * 4;
  int col = n0 + wn + l15;
  float v4[4];
#pragma unroll
  for (int rg = 0; rg < 4; ++rg) {
    float val = alpha * acc[rg];
    if (eA != 0.f) val += eA * bf2f(A[(size_t)(row0 + rg) * K + col]);
    if (row0 + rg == col) val += diagc;
    v4[rg] = val;
  }
  if (flags & 1) {
#pragma unroll
    for (int rg = 0; rg < 4; ++rg)
      Cb[cbase + (size_t)(row0 + rg) * 256 + col] = f2bf(v4[rg]);
  }
  if (flags & 2) {
    ushort4 pk;
    pk.x = f2bf(v4[0]); pk.y = f2bf(v4[1]);
    pk.z = f2bf(v4[2]); pk.w = f2bf(v4[3]);
    *(ushort4*)(CTb + cbase + (size_t)col * 256 + row0) = pk;
  }
  if (flags & 4) {
#pragma unroll
    for (int rg = 0; rg < 4; ++rg)
      Cf[cbase + (size_t)(row0 + rg) * 256 + col] = v4[rg];
  }
}

// ---- merged NS update (32-tile): z' = 0.25 z@t1 ; Y' = 0.25 Y@t1
__global__ __launch_bounds__(256) void ns_zy32(const bf16_t* __restrict__ zg,
    const bf16_t* __restrict__ Yg, const bf16_t* __restrict__ t1Tg,
    bf16_t* __restrict__ zog, bf16_t* __restrict__ Yog,
    bf16_t* __restrict__ YTog) {
  int bid = blockIdx.x;                       // 0..8191
  int orig = (bid & 7) * 1024 + (bid >> 3);   // XCD-contiguous remap
  int task = orig >> 6;                       // 0..127
  int bh = task >> 1;
  int which = task & 1;                       // 0: z-part, 1: Y-part
  int tile = orig & 63;
  int n0 = (tile & 7) << 5;
  int m0 = (tile >> 3) << 5;
  const bf16_t* A  = (which ? Yg : zg) + ((size_t)bh << 16);
  const bf16_t* BT = t1Tg + ((size_t)bh << 16);
  __shared__ short As[32][36];
  __shared__ short Bs[32][36];
  int tid = threadIdx.x;
  int lane = tid & 63;
  int wv = tid >> 6;
  int wm = (wv & 1) << 4, wn = (wv >> 1) << 4;
  int l15 = lane & 15, l16 = lane >> 4;
  f32x4 acc = (f32x4){0.f, 0.f, 0.f, 0.f};
  int ar0 = tid >> 3, ac0 = (tid & 7) << 2;
  const bf16_t* Ab = A + (size_t)(m0 + ar0) * 256 + ac0;
  const bf16_t* Bb = BT + (size_t)(n0 + ar0) * 256 + ac0;
  uint2 ga = *(const uint2*)Ab;
  uint2 gb = *(const uint2*)Bb;
  for (int k0 = 0; k0 < 256; k0 += 32) {
    *(uint2*)&As[ar0][ac0] = ga;
    *(uint2*)&Bs[ar0][ac0] = gb;
    __syncthreads();
    if (k0 + 32 < 256) {
      ga = *(const uint2*)(Ab + k0 + 32);
      gb = *(const uint2*)(Bb + k0 + 32);
    }
    bf16x8 af = *(const bf16x8*)&As[wm + l15][l16 * 8];
    bf16x8 bf = *(const bf16x8*)&Bs[wn + l15][l16 * 8];
    acc = __builtin_amdgcn_mfma_f32_16x16x32_bf16(af, bf, acc, 0, 0, 0);
    __syncthreads();
  }
  size_t cbase = (size_t)bh << 16;
  int row0 = m0 + wm + l16 * 4;
  int col = n0 + wn + l15;
  float v4[4];
#pragma unroll
  for (int rg = 0; rg < 4; ++rg) v4[rg] = 0.25f * acc[rg];
  if (which == 0) {
#pragma unroll
    for (int rg = 0; rg < 4; ++rg)
      zog[cbase + (size_t)(row0 + rg) * 256 + col] = f2bf(v4[rg]);
  } else {
#pragma unroll
    for (int rg = 0; rg < 4; ++rg)
      Yog[cbase + (size_t)(row0 + rg) * 256 + col] = f2bf(v4[rg]);
    ushort4 pk;
    pk.x = f2bf(v4[0]); pk.y = f2bf(v4[1]);
    pk.z = f2bf(v4[2]); pk.w = f2bf(v4[3]);
    *(ushort4*)(YTog + cbase + (size_t)col * 256 + row0) = pk;
  }
}

// ------------------------------------------------------------- landmark pool
__global__ __launch_bounds__(64) void pool_kernel(const bf16_t* __restrict__ q,
    const bf16_t* __restrict__ k, bf16_t* __restrict__ qlb,
    bf16_t* __restrict__ klb) {
  int bh = blockIdx.y, i = blockIdx.x, d = threadIdx.x;
  const bf16_t* qb = q + ((size_t)bh * SEQ + i * 16) * DH + d;
  const bf16_t* kb = k + ((size_t)bh * SEQ + i * 16) * DH + d;
  float sq = 0.f, sk = 0.f;
#pragma unroll
  for (int j = 0; j < 16; ++j) { sq += bf2f(qb[j * DH]); sk += bf2f(kb[j * DH]); }
  sq *= (1.f / 16.f); sk *= (1.f / 16.f);
  qlb[((size_t)bh * MLM + i) * DH + d] = f2bf(sq);
  klb[((size_t)bh * MLM + i) * DH + d] = f2bf(sk);
}

// ---------------------------------------------------- softmax rows of 256
__global__ __launch_bounds__(256) void softmax256(const float* __restrict__ af,
    bf16_t* __restrict__ ab) {
  const float* ar = af + (size_t)blockIdx.x * MLM;
  int t = threadIdx.x;
  float v = ar[t];
  __shared__ float redm[4], reds[4];
  float m = v;
#pragma unroll
  for (int off = 32; off > 0; off >>= 1) m = fmaxf(m, __shfl_xor(m, off));
  if ((t & 63) == 0) redm[t >> 6] = m;
  __syncthreads();
  m = fmaxf(fmaxf(redm[0], redm[1]), fmaxf(redm[2], redm[3]));
  float p = __expf(v - m);
  float s = p;
#pragma unroll
  for (int off = 32; off > 0; off >>= 1) s += __shfl_xor(s, off);
  if ((t & 63) == 0) reds[t >> 6] = s;
  __syncthreads();
  s = reds[0] + reds[1] + reds[2] + reds[3];
  ab[(size_t)blockIdx.x * MLM + t] = f2bf(p / s);
}

// ------------------------------------------- pinv scalars: global max sums
__global__ void init_scal(unsigned* s) { if (threadIdx.x < 2) s[threadIdx.x] = 0u; }

__global__ __launch_bounds__(256) void colrow_max(const bf16_t* __restrict__ a,
    unsigned* __restrict__ scal) {
  int bh = blockIdx.x;
  int task = blockIdx.y;
  const bf16_t* ab = a + (size_t)bh * MLM * MLM;
  int t = threadIdx.x;
  float s = 0.f;
  if (task == 0) {
    const bf16_t* rp = ab + (size_t)t * MLM;
    for (int j = 0; j < MLM; j += 8) {
      float d[8];
      unp8(rp + j, d);
      s += d[0]; s += d[1]; s += d[2]; s += d[3];
      s += d[4]; s += d[5]; s += d[6]; s += d[7];
    }
  } else {
    for (int i = 0; i < MLM; ++i) s += bf2f(ab[(size_t)i * MLM + t]);
  }
  __shared__ float red[4];
  float m = s;
#pragma unroll
  for (int off = 32; off > 0; off >>= 1) m = fmaxf(m, __shfl_xor(m, off));
  if ((t & 63) == 0) red[t >> 6] = m;
  __syncthreads();
  if (t == 0) {
    m = fmaxf(fmaxf(red[0], red[1]), fmaxf(red[2], red[3]));
    atomicMax(scal + task, __float_as_uint(m));
  }
}

// z0 = a^T / denom (bf16), z0T = a / denom (bf16)
__global__ __launch_bounds__(256) void zinit(const bf16_t* __restrict__ ab,
    bf16_t* __restrict__ z0, bf16_t* __restrict__ z0T,
    const unsigned* __restrict__ scal) {
  size_t idx = (size_t)blockIdx.x * 256 + threadIdx.x;
  float denom = __uint_as_float(scal[0]) * __uint_as_float(scal[1]);
  size_t bh = idx >> 16;
  int i = (int)((idx >> 8) & 255);
  int j = (int)(idx & 255);
  bf16_t r = f2bf(bf2f(ab[idx]) / denom);
  z0T[idx] = r;
  z0[(bh << 16) + ((size_t)j << 8) + i] = r;
}

// --------- attn3v (MFMA flash): partial softmax(q_l@k^T)@v over 512-key chunk
__global__ __launch_bounds__(64) void attn3v_mfma(const bf16_t* __restrict__ qlb,
    const bf16_t* __restrict__ kg, const bf16_t* __restrict__ vT,
    float* __restrict__ pacc, float* __restrict__ pm, float* __restrict__ ps) {
  int bid = blockIdx.x;                       // 0..4095 (4096 % 8 == 0)
  int orig = (bid & 7) * 512 + (bid >> 3);    // XCD-contiguous remap
  int m0 = (orig & 7) << 5;                   // q-row tile
  int cz = (orig >> 3) & 7;                   // 512-key chunk
  int bh = orig >> 6;                         // batch*head
  int lane = threadIdx.x;
  int l15 = lane & 15, l16 = lane >> 4;
  __shared__ short plds[32][136];
  const bf16_t* qbase = qlb + (size_t)bh * MLM * DH;
  const bf16_t* kbase = kg + (size_t)bh * SEQ * DH;
  const bf16_t* vbase = vT + (size_t)bh * DH * SEQ;
  bf16x8 af[2][2];
#pragma unroll
  for (int mt = 0; mt < 2; ++mt)
#pragma unroll
    for (int ks = 0; ks < 2; ++ks)
      af[mt][ks] = *(const bf16x8*)(qbase + (size_t)(m0 + mt * 16 + l15) * DH + ks * 32 + l16 * 8);
  float m_run[2][4], s_run[2][4];
  f32x4 o[2][4];
#pragma unroll
  for (int mt = 0; mt < 2; ++mt) {
#pragma unroll
    for (int rg = 0; rg < 4; ++rg) { m_run[mt][rg] = -1e30f; s_run[mt][rg] = 0.f; }
#pragma unroll
    for (int n2 = 0; n2 < 4; ++n2) o[mt][n2] = (f32x4){0.f, 0.f, 0.f, 0.f};
  }
  int kbeg = cz << 9;
  for (int kt = kbeg; kt < kbeg + 512; kt += 128) {
    f32x4 sacc[2][8];
#pragma unroll
    for (int mt = 0; mt < 2; ++mt)
#pragma unroll
      for (int nt = 0; nt < 8; ++nt) sacc[mt][nt] = (f32x4){0.f, 0.f, 0.f, 0.f};
#pragma unroll
    for (int nt = 0; nt < 8; ++nt) {
      const bf16_t* kr = kbase + (size_t)(kt + nt * 16 + l15) * DH + l16 * 8;
      bf16x8 b0 = *(const bf16x8*)kr;
      bf16x8 b1 = *(const bf16x8*)(kr + 32);
      sacc[0][nt] = __builtin_amdgcn_mfma_f32_16x16x32_bf16(af[0][0], b0, sacc[0][nt], 0, 0, 0);
      sacc[0][nt] = __builtin_amdgcn_mfma_f32_16x16x32_bf16(af[0][1], b1, sacc[0][nt], 0, 0, 0);
      sacc[1][nt] = __builtin_amdgcn_mfma_f32_16x16x32_bf16(af[1][0], b0, sacc[1][nt], 0, 0, 0);
      sacc[1][nt] = __builtin_amdgcn_mfma_f32_16x16x32_bf16(af[1][1], b1, sacc[1][nt], 0, 0, 0);
    }
#pragma unroll
    for (int mt = 0; mt < 2; ++mt)
#pragma unroll
      for (int rg = 0; rg < 4; ++rg) {
        float mx = sacc[mt][0][rg];
#pragma unroll
        for (int nt = 1; nt < 8; ++nt) mx = fmaxf(mx, sacc[mt][nt][rg]);
        mx = fmaxf(mx, __shfl_xor(mx, 1));
        mx = fmaxf(mx, __shfl_xor(mx, 2));
        mx = fmaxf(mx, __shfl_xor(mx, 4));
        mx = fmaxf(mx, __shfl_xor(mx, 8));
        float mnew = fmaxf(m_run[mt][rg], mx);
        float corr = __expf(m_run[mt][rg] - mnew);
        float s = 0.f;
#pragma unroll
        for (int nt = 0; nt < 8; ++nt) {
          float p = __expf(sacc[mt][nt][rg] - mnew);
          sacc[mt][nt][rg] = p;
          s += p;
        }
        s += __shfl_xor(s, 1); s += __shfl_xor(s, 2);
        s += __shfl_xor(s, 4); s += __shfl_xor(s, 8);
        s_run[mt][rg] = s_run[mt][rg] * corr + s;
        m_run[mt][rg] = mnew;
#pragma unroll
        for (int n2 = 0; n2 < 4; ++n2) o[mt][n2][rg] *= corr;
      }
#pragma unroll
    for (int mt = 0; mt < 2; ++mt)
#pragma unroll
      for (int nt = 0; nt < 8; ++nt)
#pragma unroll
        for (int rg = 0; rg < 4; ++rg)
          plds[mt * 16 + l16 * 4 + rg][nt * 16 + l15] = (short)f2bf(sacc[mt][nt][rg]);
#pragma unroll
    for (int ks2 = 0; ks2 < 4; ++ks2) {
      bf16x8 pa0 = *(const bf16x8*)&plds[l15][ks2 * 32 + l16 * 8];
      bf16x8 pa1 = *(const bf16x8*)&plds[16 + l15][ks2 * 32 + l16 * 8];
#pragma unroll
      for (int n2 = 0; n2 < 4; ++n2) {
        bf16x8 vb8 = *(const bf16x8*)(vbase + (size_t)(n2 * 16 + l15) * SEQ + kt + ks2 * 32 + l16 * 8);
        o[0][n2] = __builtin_amdgcn_mfma_f32_16x16x32_bf16(pa0, vb8, o[0][n2], 0, 0, 0);
        o[1][n2] = __builtin_amdgcn_mfma_f32_16x16x32_bf16(pa1, vb8, o[1][n2], 0, 0, 0);
      }
    }
  }
  size_t pidx0 = (size_t)(bh * 8 + cz) * MLM + m0;
#pragma unroll
  for (int mt = 0; mt < 2; ++mt)
#pragma unroll
    for (int n2 = 0; n2 < 4; ++n2)
#pragma unroll
      for (int rg = 0; rg < 4; ++rg) {
        int row = mt * 16 + l16 * 4 + rg;
        pacc[(pidx0 + row) * 64 + n2 * 16 + l15] = o[mt][n2][rg];
      }
  if (l15 == 0) {
#pragma unroll
    for (int mt = 0; mt < 2; ++mt)
#pragma unroll
      for (int rg = 0; rg < 4; ++rg) {
        pm[pidx0 + mt * 16 + l16 * 4 + rg] = m_run[mt][rg];
        ps[pidx0 + mt * 16 + l16 * 4 + rg] = s_run[mt][rg];
      }
  }
}

// --------------- attn3v phase 2: combine 8 chunk-partials -> a3v bf16
__global__ __launch_bounds__(256) void attn3v_comb(const float* __restrict__ pacc,
    const float* __restrict__ pm, const float* __restrict__ ps,
    bf16_t* __restrict__ a3vb) {
  int gw = blockIdx.x * 4 + (threadIdx.x >> 6);  // row id 0..16383
  int lane = threadIdx.x & 63;
  int bh = gw >> 8, row = gw & 255;
  float ms[8];
  float M = -1e30f;
#pragma unroll
  for (int cc = 0; cc < 8; ++cc) {
    ms[cc] = pm[(size_t)(bh * 8 + cc) * MLM + row];
    M = fmaxf(M, ms[cc]);
  }
  float S = 0.f, val = 0.f;
#pragma unroll
  for (int cc = 0; cc < 8; ++cc) {
    size_t pidx = (size_t)(bh * 8 + cc) * MLM + row;
    float w = __expf(ms[cc] - M);
    S += w * ps[pidx];
    val += w * pacc[pidx * 64 + lane];
  }
  a3vb[(size_t)gw * 64 + lane] = f2bf(val / S);
}

// ---------------- wm^T = (zc @ a3v)^T  bf16 [bh][64][256]
__global__ __launch_bounds__(256) void wm_kernel(const bf16_t* __restrict__ zb,
    const bf16_t* __restrict__ a3vb, bf16_t* __restrict__ wmT) {
  int bh = blockIdx.y;
  int m0 = blockIdx.x << 6;
  __shared__ bf16_t a3s[MLM * DH];
  int t = threadIdx.x;
  const bf16_t* asrc = a3vb + (size_t)bh * MLM * DH;
#pragma unroll
  for (int i = 0; i < 8; ++i)
    *(bf16x8*)(a3s + ((size_t)t + 256 * i) * 8) =
        *(const bf16x8*)(asrc + ((size_t)t + 256 * i) * 8);
  __syncthreads();
  int row = m0 + (t >> 2);
  int c0 = (t & 3) * 16;
  const bf16_t* zrow = zb + (size_t)bh * 65536 + (size_t)row * 256;
  float acc16[16] = {};
  for (int k0 = 0; k0 < 256; k0 += 8) {
    float a8[8];
    unp8(zrow + k0, a8);
#pragma unroll
    for (int j = 0; j < 8; ++j) {
      float av[16];
      unp8(a3s + (k0 + j) * 64 + c0, av);
      unp8(a3s + (k0 + j) * 64 + c0 + 8, av + 8);
#pragma unroll
      for (int e = 0; e < 16; ++e) acc16[e] += a8[j] * av[e];
    }
  }
  bf16_t* wd = wmT + (size_t)bh * DH * MLM;
#pragma unroll
  for (int e = 0; e < 16; ++e)
    wd[(size_t)(c0 + e) * MLM + row] = f2bf(acc16[e]);
}

// ---------- attn1 (MFMA): om = softmax(q @ k_l^T) @ W, one wave = 32 q-rows
__global__ __launch_bounds__(64) void attn1_mfma(const bf16_t* __restrict__ qg,
    const bf16_t* __restrict__ klb, const bf16_t* __restrict__ wmT,
    bf16_t* __restrict__ om) {
  int bh = blockIdx.y, bat = bh >> 3, head = bh & 7;
  int m0 = blockIdx.x << 5;
  int lane = threadIdx.x;
  int l15 = lane & 15, l16 = lane >> 4;
  __shared__ short plds[32][264];
  const bf16_t* qbase = qg + (size_t)bh * SEQ * DH;
  const bf16_t* kbase = klb + (size_t)bh * MLM * DH;
  bf16x8 af[2][2];
#pragma unroll
  for (int mt = 0; mt < 2; ++mt)
#pragma unroll
    for (int ks = 0; ks < 2; ++ks)
      af[mt][ks] = *(const bf16x8*)(qbase + (size_t)(m0 + mt * 16 + l15) * DH + ks * 32 + l16 * 8);
  f32x4 acc[2][16];
#pragma unroll
  for (int mt = 0; mt < 2; ++mt)
#pragma unroll
    for (int nt = 0; nt < 16; ++nt) acc[mt][nt] = (f32x4){0.f, 0.f, 0.f, 0.f};
#pragma unroll
  for (int nt = 0; nt < 16; ++nt) {
    bf16x8 b0 = *(const bf16x8*)(kbase + (size_t)(nt * 16 + l15) * DH + l16 * 8);
    bf16x8 b1 = *(const bf16x8*)(kbase + (size_t)(nt * 16 + l15) * DH + 32 + l16 * 8);
    acc[0][nt] = __builtin_amdgcn_mfma_f32_16x16x32_bf16(af[0][0], b0, acc[0][nt], 0, 0, 0);
    acc[0][nt] = __builtin_amdgcn_mfma_f32_16x16x32_bf16(af[0][1], b1, acc[0][nt], 0, 0, 0);
    acc[1][nt] = __builtin_amdgcn_mfma_f32_16x16x32_bf16(af[1][0], b0, acc[1][nt], 0, 0, 0);
    acc[1][nt] = __builtin_amdgcn_mfma_f32_16x16x32_bf16(af[1][1], b1, acc[1][nt], 0, 0, 0);
  }
  float inv[2][4];
#pragma unroll
  for (int mt = 0; mt < 2; ++mt)
#pragma unroll
    for (int rg = 0; rg < 4; ++rg) {
      float mx = acc[mt][0][rg];
#pragma unroll
      for (int nt = 1; nt < 16; ++nt) mx = fmaxf(mx, acc[mt][nt][rg]);
      mx = fmaxf(mx, __shfl_xor(mx, 1));
      mx = fmaxf(mx, __shfl_xor(mx, 2));
      mx = fmaxf(mx, __shfl_xor(mx, 4));
      mx = fmaxf(mx, __shfl_xor(mx, 8));
      float s = 0.f;
#pragma unroll
      for (int nt = 0; nt < 16; ++nt) {
        float p = __expf(acc[mt][nt][rg] - mx);
        acc[mt][nt][rg] = p;
        s += p;
      }
      s += __shfl_xor(s, 1); s += __shfl_xor(s, 2);
      s += __shfl_xor(s, 4); s += __shfl_xor(s, 8);
      inv[mt][rg] = 1.f / s;
    }
#pragma unroll
  for (int mt = 0; mt < 2; ++mt)
#pragma unroll
    for (int nt = 0; nt < 16; ++nt)
#pragma unroll
      for (int rg = 0; rg < 4; ++rg)
        plds[mt * 16 + l16 * 4 + rg][nt * 16 + l15] = (short)f2bf(acc[mt][nt][rg]);
  const bf16_t* wbase = wmT + (size_t)bh * DH * MLM;
  f32x4 o[2][4];
#pragma unroll
  for (int mt = 0; mt < 2; ++mt)
#pragma unroll
    for (int n2 = 0; n2 < 4; ++n2) o[mt][n2] = (f32x4){0.f, 0.f, 0.f, 0.f};
#pragma unroll
  for (int ks = 0; ks < 8; ++ks) {
    bf16x8 pa0 = *(const bf16x8*)&plds[l15][ks * 32 + l16 * 8];
    bf16x8 pa1 = *(const bf16x8*)&plds[16 + l15][ks * 32 + l16 * 8];
#pragma unroll
    for (int n2 = 0; n2 < 4; ++n2) {
      bf16x8 wb = *(const bf16x8*)(wbase + (size_t)(n2 * 16 + l15) * MLM + ks * 32 + l16 * 8);
      o[0][n2] = __builtin_amdgcn_mfma_f32_16x16x32_bf16(pa0, wb, o[0][n2], 0, 0, 0);
      o[1][n2] = __builtin_amdgcn_mfma_f32_16x16x32_bf16(pa1, wb, o[1][n2], 0, 0, 0);
    }
  }
#pragma unroll
  for (int mt = 0; mt < 2; ++mt)
#pragma unroll
    for (int n2 = 0; n2 < 4; ++n2)
#pragma unroll
      for (int rg = 0; rg < 4; ++rg) {
        int n = m0 + mt * 16 + l16 * 4 + rg;
        int d = n2 * 16 + l15;
        om[((size_t)(bat * SEQ + n)) * DMODEL + head * DH + d] =
            f2bf(o[mt][n2][rg] * inv[mt][rg]);
      }
}

// --------------------- depthwise conv(v) added into om (bf16 RMW)
__global__ __launch_bounds__(256) void conv_add(const bf16_t* __restrict__ vg,
    const float* __restrict__ rk, bf16_t* __restrict__ om) {
  int bh = blockIdx.y, bat = bh >> 3, head = bh & 7;
  int n0 = blockIdx.x << 5;
  __shared__ bf16_t vs[64 * 64];
  int t = threadIdx.x;
  const bf16_t* vbase = vg + (size_t)bh * SEQ * DH;
#pragma unroll
  for (int i = 0; i < 2; ++i) {
    int li = t + 256 * i;
    int rr = li >> 3, cc = (li & 7) << 3;
    int src = n0 - 16 + rr;
    bf16x8 val;
    if (src >= 0 && src < SEQ) val = *(const bf16x8*)(vbase + (size_t)src * DH + cc);
    else { short z = 0; val = (bf16x8){z, z, z, z, z, z, z, z}; }
    *(bf16x8*)(vs + rr * 64 + cc) = val;
  }
  __syncthreads();
  float w[33];
#pragma unroll
  for (int i = 0; i < 33; ++i) w[i] = rk[head * 33 + i];
  int d = t & 63;
  int r0 = (t >> 6) << 3;
  float out[8] = {0.f, 0.f, 0.f, 0.f, 0.f, 0.f, 0.f, 0.f};
#pragma unroll
  for (int j = 0; j < 40; ++j) {
    float vv = bf2f(vs[(r0 + j) * 64 + d]);
    int ilo = j - 32; if (ilo < 0) ilo = 0;
    int ihi = j; if (ihi > 7) ihi = 7;
    for (int i = ilo; i <= ihi; ++i) out[i] += w[j - i] * vv;
  }
#pragma unroll
  for (int i = 0; i < 8; ++i) {
    int n = n0 + r0 + i;
    size_t idx = ((size_t)(bat * SEQ + n)) * DMODEL + head * DH + d;
    om[idx] = f2bf(bf2f(om[idx]) + out[i]);
  }
}

// ---------------------------------------------------------------- launcher
extern "C" void kernel_launch(void* const* d_in, const int* in_sizes, int n_in,
                              void* d_out, int out_size, void* d_ws, size_t ws_size,
                              hipStream_t stream) {
  const float* x     = (const float*)d_in[0];
  const float* gamma = (const float*)d_in[1];
  const float* beta  = (const float*)d_in[2];
  const float* w_qkv = (const float*)d_in[3];
  const float* w_out = (const float*)d_in[4];
  const float* b_out = (const float*)d_in[5];
  const float* rk    = (const float*)d_in[6];
  float* y  = (float*)d_out;

  // ---- workspace layout (221.3 MB total) ----
  bf16_t* xnb  = (bf16_t*)d_ws;           // 16777216 (reused as om)
  bf16_t* qb   = xnb + 16777216;
  bf16_t* kb   = qb + 16777216;
  bf16_t* vb   = kb + 16777216;
  bf16_t* wqkvT = vb + 16777216;          // 786432
  bf16_t* woutT = wqkvT + 786432;         // 262144
  bf16_t* qlb  = woutT + 262144;          // 1048576
  bf16_t* klb  = qlb + 1048576;           // 1048576
  bf16_t* a2b  = klb + 1048576;           // 4194304
  // NS slots (4 x 4194304): zA/zB (z ping-pong), Ya/Yb (Y ping-pong)
  bf16_t* zA   = a2b + 4194304;
  bf16_t* z0T  = zA + 4194304;            // z0T for Y0 GEMM; then reused as Yb
  bf16_t* zB   = z0T + 4194304;
  bf16_t* Ya   = zB + 4194304;
  bf16_t* Yb   = z0T;                     // alias (z0T dead after Y0 GEMM)
  bf16_t* vTb  = zA;                      // alias: vT [bh][64][4096] (dead before zinit)
  bf16_t* a3vb = Ya + 4194304;            // 1048576
  bf16_t* wmT  = a3vb + 1048576;          // 1048576
  // shared region SR (33.55 MB): a2f32 -> pacc -> {YTa, YTb, t2T, t1T}
  float*  SR   = (float*)(wmT + 1048576); // 8388608 f32
  float*  a2f  = SR;
  float*  pacc = SR;
  bf16_t* YTa  = (bf16_t*)SR;
  bf16_t* YTb  = YTa + 4194304;
  bf16_t* t2T  = YTa + 8388608;
  bf16_t* t1T  = YTa + 12582912;
  float*  pm   = SR + 8388608;            // 131072
  float*  ps   = pm + 131072;             // 131072
  unsigned* scal = (unsigned*)(ps + 131072);
  size_t need = (size_t)93323264 * 2 + (size_t)(8388608 + 262144) * 4 + 64;
  if (ws_size < need) return;  // clean fail instead of OOB fault

  ln_kernel<<<NROWS, 64, 0, stream>>>(x, gamma, beta, xnb);
  convT<<<3072, 256, 0, stream>>>(w_qkv, wqkvT, 512, 1536);
  convT<<<1024, 256, 0, stream>>>(w_out, woutT, 512, 512);

  gemm_qkv_256<<<768, 512, 0, stream>>>(xnb, wqkvT, qb, kb, vb, vTb);
  pool_kernel<<<dim3(MLM, NBH), 64, 0, stream>>>(qb, kb, qlb, klb);

  // sim2 = q_l @ k_l^T (32-tile MFMA, f32 out), softmax -> a2b bf16
  bmm_mfma32<<<4096, 256, 0, stream>>>(qlb, klb, nullptr, nullptr, a2f,
      64, 1.f, 0.f, 0.f, 4);
  softmax256<<<NBH * MLM, 256, 0, stream>>>(a2f, a2b);

  init_scal<<<1, 64, 0, stream>>>(scal);
  colrow_max<<<dim3(NBH, 2), 256, 0, stream>>>(a2b, scal);

  // attn3v split-K MFMA flash, XCD-swizzled (vT aliases NS region; dead after)
  attn3v_mfma<<<4096, 64, 0, stream>>>(qlb, kb, vTb, pacc, pm, ps);
  attn3v_comb<<<4096, 256, 0, stream>>>(pacc, pm, ps, a3vb);

  // pinv via Y-tracking chain, 32-tile GEMMs
  zinit<<<16384, 256, 0, stream>>>(a2b, zA, z0T, scal);
  // Y0 = a2 @ z0  (= a2@a2^T/c): A=a2, BT=z0T -> Ya + YTa
  bmm_mfma32<<<4096, 256, 0, stream>>>(a2b, z0T, Ya, YTa, nullptr,
      256, 1.f, 0.f, 0.f, 3);
  bf16_t* zc = zA;  bf16_t* zo = zB;
  bf16_t* Yc = Ya;  bf16_t* YTc = YTa;
  bf16_t* Yo = Yb;  bf16_t* YTo = YTb;
  for (int it = 0; it < 6; ++it) {
    // t2 = Y@Y - 7Y + 15I  -> t2T
    bmm_mfma32<<<4096, 256, 0, stream>>>(Yc, YTc, nullptr, t2T, nullptr,
        256, 1.f, -7.f, 15.f, 2);
    // t1 = 13I - Y@t2      -> t1T
    bmm_mfma32<<<4096, 256, 0, stream>>>(Yc, t2T, nullptr, t1T, nullptr,
        256, -1.f, 0.f, 13.f, 2);
    // z' = 0.25 z@t1 ; Y' = 0.25 Y@t1 (merged, 8192 blocks)
    ns_zy32<<<8192, 256, 0, stream>>>(zc, Yc, t1T, zo, Yo, YTo);
    bf16_t* tp;
    tp = zc; zc = zo; zo = tp;
    tp = Yc; Yc = Yo; Yo = tp;
    tp = YTc; YTc = YTo; YTo = tp;
  }
  // zc == zA after even number of swaps

  // wm^T = (z6 @ a3v)^T
  wm_kernel<<<dim3(4, NBH), 256, 0, stream>>>(zc, a3vb, wmT);

  // attn1 (MFMA) -> om, then depthwise conv added
  bf16_t* om = xnb;
  attn1_mfma<<<dim3(SEQ / 32, NBH), 64, 0, stream>>>(qb, klb, wmT, om);
  conv_add<<<dim3(SEQ / 32, NBH), 256, 0, stream>>>(vb, rk, om);

  // y = x + om @ w_out + b_out
  gemm_out_mfma<<<1024, 256, 0, stream>>>(om, woutT, b_out, x, y);
}

// Round 3
// 757.993 us; speedup vs baseline: 1.0171x; 1.0117x over previous
//
#include <hip/hip_runtime.h>

#define SEQ 4096
#define DMODEL 512
#define NH 8
#define DH 64
#define MLM 256
#define NBH 64          // B*H = 8*8
#define NROWS 32768     // B*SEQ

typedef unsigned short bf16_t;
typedef __attribute__((ext_vector_type(8))) short bf16x8;
typedef __attribute__((ext_vector_type(4))) float f32x4;

__device__ __forceinline__ float bf2f(unsigned short u) {
  return __uint_as_float(((unsigned)u) << 16);
}
__device__ __forceinline__ unsigned short f2bf(float f) {
  unsigned u = __float_as_uint(f);
  u += 0x7fffu + ((u >> 16) & 1u);
  return (unsigned short)(u >> 16);
}
// unpack 8 consecutive bf16 at p into d[0..7]
__device__ __forceinline__ void unp8(const bf16_t* p, float* d) {
  uint4 u = *(const uint4*)p;
  d[0] = __uint_as_float(u.x << 16); d[1] = __uint_as_float(u.x & 0xffff0000u);
  d[2] = __uint_as_float(u.y << 16); d[3] = __uint_as_float(u.y & 0xffff0000u);
  d[4] = __uint_as_float(u.z << 16); d[5] = __uint_as_float(u.z & 0xffff0000u);
  d[6] = __uint_as_float(u.w << 16); d[7] = __uint_as_float(u.w & 0xffff0000u);
}

// async global->LDS, 16B per lane, wave-uniform LDS base + lane*16 (m104)
__device__ __forceinline__ void gll(const void* g, void* l) {
  __builtin_amdgcn_global_load_lds(
      (const __attribute__((address_space(1))) unsigned int*)g,
      (__attribute__((address_space(3))) unsigned int*)l, 16, 0, 0);
}

// ---------------------------------------------------------------- LayerNorm
__global__ __launch_bounds__(64) void ln_kernel(const float* __restrict__ x,
    const float* __restrict__ gamma, const float* __restrict__ beta,
    bf16_t* __restrict__ xn) {
  int row = blockIdx.x;
  const float4* xr = (const float4*)(x + (size_t)row * DMODEL);
  int t = threadIdx.x;
  float4 a = xr[t], b = xr[t + 64];
  float s  = a.x + a.y + a.z + a.w + b.x + b.y + b.z + b.w;
  float ss = a.x*a.x + a.y*a.y + a.z*a.z + a.w*a.w
           + b.x*b.x + b.y*b.y + b.z*b.z + b.w*b.w;
#pragma unroll
  for (int off = 32; off > 0; off >>= 1) {
    s  += __shfl_xor(s, off);
    ss += __shfl_xor(ss, off);
  }
  float mean = s * (1.0f / DMODEL);
  float var  = ss * (1.0f / DMODEL) - mean * mean;
  float rstd = rsqrtf(var + 1e-5f);
  const float4* g4 = (const float4*)gamma;
  const float4* be4 = (const float4*)beta;
  ushort4* o = (ushort4*)(xn + (size_t)row * DMODEL);
  float4 g = g4[t], bb = be4[t];
  ushort4 r;
  r.x = f2bf((a.x - mean) * rstd * g.x + bb.x);
  r.y = f2bf((a.y - mean) * rstd * g.y + bb.y);
  r.z = f2bf((a.z - mean) * rstd * g.z + bb.z);
  r.w = f2bf((a.w - mean) * rstd * g.w + bb.w);
  o[t] = r;
  g = g4[t + 64]; bb = be4[t + 64];
  r.x = f2bf((b.x - mean) * rstd * g.x + bb.x);
  r.y = f2bf((b.y - mean) * rstd * g.y + bb.y);
  r.z = f2bf((b.z - mean) * rstd * g.z + bb.z);
  r.w = f2bf((b.w - mean) * rstd * g.w + bb.w);
  o[t + 64] = r;
}

// ------------------------------------- weight convert + transpose (fp32->bf16)
__global__ __launch_bounds__(256) void convT(const float* __restrict__ w,
    bf16_t* __restrict__ wt, int K, int N) {
  size_t idx = (size_t)blockIdx.x * 256 + threadIdx.x;
  int n = (int)(idx / K), k = (int)(idx % K);
  wt[idx] = f2bf(w[(size_t)k * N + n]);
}

// ----------------------- MFMA 128x128 tile GEMM body (A, BT bf16 row-major-K)
// global_load_lds width-16 staging, unpadded [128][32] LDS (wave-linear dest).
#define MFMA_GEMM_BODY(APTR, BTPTR, KDIM) \
  __shared__ short As[128][32]; \
  __shared__ short Bs[128][32]; \
  int tid = threadIdx.x; \
  int lane = tid & 63; \
  int wv = tid >> 6; \
  int wm = (wv & 1) << 6, wn = (wv >> 1) << 6; \
  int l15 = lane & 15, l16 = lane >> 4; \
  f32x4 acc[4][4]; \
  _Pragma("unroll") for (int fm = 0; fm < 4; ++fm) \
    _Pragma("unroll") for (int fn = 0; fn < 4; ++fn) \
      acc[fm][fn] = (f32x4){0.f, 0.f, 0.f, 0.f}; \
  int ar0 = tid >> 2, ac0 = (tid & 3) << 3; \
  const bf16_t* Ab  = (APTR) + (size_t)(m0 + ar0) * (KDIM) + ac0; \
  const bf16_t* Ab1 = (APTR) + (size_t)(m0 + ar0 + 64) * (KDIM) + ac0; \
  const bf16_t* Bb  = (BTPTR) + (size_t)(n0 + ar0) * (KDIM) + ac0; \
  const bf16_t* Bb1 = (BTPTR) + (size_t)(n0 + ar0 + 64) * (KDIM) + ac0; \
  short* AsW  = &As[(wv << 4)][0]; \
  short* AsW1 = &As[64 + (wv << 4)][0]; \
  short* BsW  = &Bs[(wv << 4)][0]; \
  short* BsW1 = &Bs[64 + (wv << 4)][0]; \
  for (int k0 = 0; k0 < (KDIM); k0 += 32) { \
    gll(Ab + k0, AsW);  gll(Ab1 + k0, AsW1); \
    gll(Bb + k0, BsW);  gll(Bb1 + k0, BsW1); \
    __syncthreads(); \
    bf16x8 af[4], bfr[4]; \
    _Pragma("unroll") for (int f = 0; f < 4; ++f) { \
      af[f]  = *(const bf16x8*)&As[wm + f * 16 + l15][l16 * 8]; \
      bfr[f] = *(const bf16x8*)&Bs[wn + f * 16 + l15][l16 * 8]; \
    } \
    _Pragma("unroll") for (int fm = 0; fm < 4; ++fm) \
      _Pragma("unroll") for (int fn = 0; fn < 4; ++fn) \
        acc[fm][fn] = __builtin_amdgcn_mfma_f32_16x16x32_bf16(af[fm], bfr[fn], acc[fm][fn], 0, 0, 0); \
    __syncthreads(); \
  }

// ======================= QKV projection: 256x256 tile, BK=32, 8 waves,
// 4-slot LDS ring + counted vmcnt pipeline, k-slot XOR swizzle, setprio.
// Epilogue: writes q (scaled), k, vT (packed) AND fused landmark pooling
// (each 16x16 C-fragment = one 16-row landmark group: 3 adds + 2 shfl_xor).
// v row-major output dropped (conv_add now reads vT).
__global__ __launch_bounds__(512) void gemm_qkv_256(const bf16_t* __restrict__ A,
    const bf16_t* __restrict__ BT, bf16_t* __restrict__ q, bf16_t* __restrict__ k,
    bf16_t* __restrict__ vT, bf16_t* __restrict__ qlb, bf16_t* __restrict__ klb) {
  int bid = blockIdx.x;                        // 0..767 (768 % 8 == 0)
  int orig = (bid & 7) * 96 + (bid >> 3);      // XCD-contiguous remap
  int n0 = (orig % 6) << 8;
  int m0 = (orig / 6) << 8;
  __shared__ short As[4][8192];                // 4 slots x [256 rows][32 k]
  __shared__ short Bs[4][8192];                // 128 KiB total
  int tid = threadIdx.x;
  int lane = tid & 63;
  int wid = tid >> 6;                          // 0..7
  int wr = wid >> 2, wc = wid & 3;             // 2M x 4N wave grid
  int l15 = lane & 15, l16 = lane >> 4;
  // k-slot XOR swizzle: LDS[row][slot] holds global k-slot (slot ^ (row&3)).
  int sl = (l16 ^ (l15 & 3)) << 3;             // element offset in row
  int gr  = lane >> 2;
  int gcs = ((lane & 3) ^ ((lane >> 2) & 3)) << 3;
  f32x4 acc[8][4];
#pragma unroll
  for (int fm = 0; fm < 8; ++fm)
#pragma unroll
    for (int fn = 0; fn < 4; ++fn) acc[fm][fn] = (f32x4){0.f, 0.f, 0.f, 0.f};

#define STAGE(kt, s) { \
    _Pragma("unroll") for (int u = 0; u < 2; ++u) { \
      int r0 = (wid << 5) + (u << 4); \
      gll(A  + (size_t)(m0 + r0 + gr) * 512 + (kt) * 32 + gcs, &As[s][r0 << 5]); \
      gll(BT + (size_t)(n0 + r0 + gr) * 512 + (kt) * 32 + gcs, &Bs[s][r0 << 5]); \
    } }

  STAGE(0, 0) STAGE(1, 1) STAGE(2, 2)          // 12 loads in flight
  for (int t = 0; t < 16; ++t) {
    int s = t & 3;
    if (t < 14)       asm volatile("s_waitcnt vmcnt(8)" ::: "memory");
    else if (t == 14) asm volatile("s_waitcnt vmcnt(4)" ::: "memory");
    else              asm volatile("s_waitcnt vmcnt(0)" ::: "memory");
    __builtin_amdgcn_s_barrier();
    if (t + 3 < 16) STAGE(t + 3, ((t + 3) & 3))
    bf16x8 a[8], b[4];
#pragma unroll
    for (int fm = 0; fm < 8; ++fm)
      a[fm] = *(const bf16x8*)&As[s][(((wr << 7) + (fm << 4) + l15) << 5) + sl];
#pragma unroll
    for (int fn = 0; fn < 4; ++fn)
      b[fn] = *(const bf16x8*)&Bs[s][(((wc << 6) + (fn << 4) + l15) << 5) + sl];
    asm volatile("s_waitcnt lgkmcnt(0)" ::: "memory");
    __builtin_amdgcn_sched_barrier(0);
    __builtin_amdgcn_s_setprio(1);
#pragma unroll
    for (int fm = 0; fm < 8; ++fm)
#pragma unroll
      for (int fn = 0; fn < 4; ++fn)
        acc[fm][fn] = __builtin_amdgcn_mfma_f32_16x16x32_bf16(a[fm], b[fn], acc[fm][fn], 0, 0, 0);
    __builtin_amdgcn_s_setprio(0);
  }
#undef STAGE
  // ---- epilogue: q/k scalar stores + fused landmark pool; vT packed stores
#pragma unroll
  for (int fm = 0; fm < 8; ++fm) {
    int row0 = m0 + (wr << 7) + (fm << 4) + (l16 << 2);
    int bat = row0 >> 12;
    int nn0 = row0 & 4095;
    int lm  = nn0 >> 4;                        // landmark id (uniform over l16,rg)
#pragma unroll
    for (int fn = 0; fn < 4; ++fn) {
      int col = n0 + (wc << 6) + (fn << 4) + l15;
      int which = col >> 9;
      int hd = (col >> 6) & 7;
      int d  = col & 63;
      if (which == 2) {
        ushort4 pk;
        pk.x = f2bf(acc[fm][fn][0]); pk.y = f2bf(acc[fm][fn][1]);
        pk.z = f2bf(acc[fm][fn][2]); pk.w = f2bf(acc[fm][fn][3]);
        *(ushort4*)(vT + ((size_t)(bat * NH + hd) * DH + d) * SEQ + nn0) = pk;
      } else {
        bf16_t* dst = (which == 0) ? q : k;
        float scale = (which == 0) ? 0.125f : 1.f;
#pragma unroll
        for (int rg = 0; rg < 4; ++rg)
          dst[(((size_t)(bat * NH + hd)) * SEQ + nn0 + rg) * DH + d] = f2bf(acc[fm][fn][rg] * scale);
        // fused landmark pool: mean over the fragment's 16 rows
        float s = acc[fm][fn][0] + acc[fm][fn][1] + acc[fm][fn][2] + acc[fm][fn][3];
        s += __shfl_xor(s, 16);
        s += __shfl_xor(s, 32);
        if (l16 == 0) {
          bf16_t* pdst = (which == 0) ? qlb : klb;
          pdst[((size_t)(bat * NH + hd) * MLM + lm) * DH + d] = f2bf(s * scale * 0.0625f);
        }
      }
    }
  }
}

// Output projection (MFMA), XCD-swizzled: y = x + om(bf16) @ woutT^T + b_out
__global__ __launch_bounds__(256) void gemm_out_mfma(const bf16_t* __restrict__ A,
    const bf16_t* __restrict__ BT, const float* __restrict__ bias,
    const float* __restrict__ x, float* __restrict__ y) {
  int bid = blockIdx.x;                        // 0..1023
  int orig = (bid & 7) * 128 + (bid >> 3);     // XCD-contiguous remap
  int n0 = (orig & 3) << 7;
  int m0 = (orig >> 2) << 7;
  MFMA_GEMM_BODY(A, BT, 512)
#pragma unroll
  for (int fm = 0; fm < 4; ++fm) {
#pragma unroll
    for (int fn = 0; fn < 4; ++fn) {
      int col = n0 + wn + fn * 16 + l15;
      float bv = bias[col];
#pragma unroll
      for (int rg = 0; rg < 4; ++rg) {
        int row = m0 + wm + fm * 16 + l16 * 4 + rg;
        y[(size_t)row * DMODEL + col] = x[(size_t)row * DMODEL + col] + acc[fm][fn][rg] + bv;
      }
    }
  }
}

// ---- 32x32-tile batched MFMA GEMM over 256x256 matrices.
__global__ __launch_bounds__(256) void bmm_mfma32(const bf16_t* __restrict__ Ag,
    const bf16_t* __restrict__ BTg, bf16_t* __restrict__ Cb,
    bf16_t* __restrict__ CTb, float* __restrict__ Cf,
    int K, float alpha, float eA, float diagc, int flags) {
  int bid = blockIdx.x;                       // 0..4095
  int orig = (bid & 7) * 512 + (bid >> 3);    // XCD-contiguous remap
  int bh = orig >> 6;
  int tile = orig & 63;
  int n0 = (tile & 7) << 5;
  int m0 = (tile >> 3) << 5;
  const bf16_t* A  = Ag + (size_t)bh * 256 * K;
  const bf16_t* BT = BTg + (size_t)bh * 256 * K;
  __shared__ short As[32][36];
  __shared__ short Bs[32][36];
  int tid = threadIdx.x;
  int lane = tid & 63;
  int wv = tid >> 6;
  int wm = (wv & 1) << 4, wn = (wv >> 1) << 4;
  int l15 = lane & 15, l16 = lane >> 4;
  f32x4 acc = (f32x4){0.f, 0.f, 0.f, 0.f};
  int ar0 = tid >> 3, ac0 = (tid & 7) << 2;
  const bf16_t* Ab = A + (size_t)(m0 + ar0) * K + ac0;
  const bf16_t* Bb = BT + (size_t)(n0 + ar0) * K + ac0;
  uint2 ga = *(const uint2*)Ab;
  uint2 gb = *(const uint2*)Bb;
  for (int k0 = 0; k0 < K; k0 += 32) {
    *(uint2*)&As[ar0][ac0] = ga;
    *(uint2*)&Bs[ar0][ac0] = gb;
    __syncthreads();
    if (k0 + 32 < K) {
      ga = *(const uint2*)(Ab + k0 + 32);
      gb = *(const uint2*)(Bb + k0 + 32);
    }
    bf16x8 af = *(const bf16x8*)&As[wm + l15][l16 * 8];
    bf16x8 bf = *(const bf16x8*)&Bs[wn + l15][l16 * 8];
    acc = __builtin_amdgcn_mfma_f32_16x16x32_bf16(af, bf, acc, 0, 0, 0);
    __syncthreads();
  }
  size_t cbase = (size_t)bh * 65536;
  int row0 = m0 + wm + l16 * 4;
  int col = n0 + wn + l15;
  float v4[4];
#pragma unroll
  for (int rg = 0; rg < 4; ++rg) {
    float val = alpha * acc[rg];
    if (eA != 0.f) val += eA * bf2f(A[(size_t)(row0 + rg) * K + col]);
    if (row0 + rg == col) val += diagc;
    v4[rg] = val;
  }
  if (flags & 1) {
#pragma unroll
    for (int rg = 0; rg < 4; ++rg)
      Cb[cbase + (size_t)(row0 + rg) * 256 + col] = f2bf(v4[rg]);
  }
  if (flags & 2) {
    ushort4 pk;
    pk.x = f2bf(v4[0]); pk.y = f2bf(v4[1]);
    pk.z = f2bf(v4[2]); pk.w = f2bf(v4[3]);
    *(ushort4*)(CTb + cbase + (size_t)col * 256 + row0) = pk;
  }
  if (flags & 4) {
#pragma unroll
    for (int rg = 0; rg < 4; ++rg)
      Cf[cbase + (size_t)(row0 + rg) * 256 + col] = v4[rg];
  }
}

// ---- merged NS update (32-tile): z' = 0.25 z@t1 ; Y' = 0.25 Y@t1
__global__ __launch_bounds__(256) void ns_zy32(const bf16_t* __restrict__ zg,
    const bf16_t* __restrict__ Yg, const bf16_t* __restrict__ t1Tg,
    bf16_t* __restrict__ zog, bf16_t* __restrict__ Yog,
    bf16_t* __restrict__ YTog) {
  int bid = blockIdx.x;                       // 0..8191
  int orig = (bid & 7) * 1024 + (bid >> 3);   // XCD-contiguous remap
  int task = orig >> 6;                       // 0..127
  int bh = task >> 1;
  int which = task & 1;                       // 0: z-part, 1: Y-part
  int tile = orig & 63;
  int n0 = (tile & 7) << 5;
  int m0 = (tile >> 3) << 5;
  const bf16_t* A  = (which ? Yg : zg) + ((size_t)bh << 16);
  const bf16_t* BT = t1Tg + ((size_t)bh << 16);
  __shared__ short As[32][36];
  __shared__ short Bs[32][36];
  int tid = threadIdx.x;
  int lane = tid & 63;
  int wv = tid >> 6;
  int wm = (wv & 1) << 4, wn = (wv >> 1) << 4;
  int l15 = lane & 15, l16 = lane >> 4;
  f32x4 acc = (f32x4){0.f, 0.f, 0.f, 0.f};
  int ar0 = tid >> 3, ac0 = (tid & 7) << 2;
  const bf16_t* Ab = A + (size_t)(m0 + ar0) * 256 + ac0;
  const bf16_t* Bb = BT + (size_t)(n0 + ar0) * 256 + ac0;
  uint2 ga = *(const uint2*)Ab;
  uint2 gb = *(const uint2*)Bb;
  for (int k0 = 0; k0 < 256; k0 += 32) {
    *(uint2*)&As[ar0][ac0] = ga;
    *(uint2*)&Bs[ar0][ac0] = gb;
    __syncthreads();
    if (k0 + 32 < 256) {
      ga = *(const uint2*)(Ab + k0 + 32);
      gb = *(const uint2*)(Bb + k0 + 32);
    }
    bf16x8 af = *(const bf16x8*)&As[wm + l15][l16 * 8];
    bf16x8 bf = *(const bf16x8*)&Bs[wn + l15][l16 * 8];
    acc = __builtin_amdgcn_mfma_f32_16x16x32_bf16(af, bf, acc, 0, 0, 0);
    __syncthreads();
  }
  size_t cbase = (size_t)bh << 16;
  int row0 = m0 + wm + l16 * 4;
  int col = n0 + wn + l15;
  float v4[4];
#pragma unroll
  for (int rg = 0; rg < 4; ++rg) v4[rg] = 0.25f * acc[rg];
  if (which == 0) {
#pragma unroll
    for (int rg = 0; rg < 4; ++rg)
      zog[cbase + (size_t)(row0 + rg) * 256 + col] = f2bf(v4[rg]);
  } else {
#pragma unroll
    for (int rg = 0; rg < 4; ++rg)
      Yog[cbase + (size_t)(row0 + rg) * 256 + col] = f2bf(v4[rg]);
    ushort4 pk;
    pk.x = f2bf(v4[0]); pk.y = f2bf(v4[1]);
    pk.z = f2bf(v4[2]); pk.w = f2bf(v4[3]);
    *(ushort4*)(YTog + cbase + (size_t)col * 256 + row0) = pk;
  }
}

// ---------------------------------------------------- softmax rows of 256
__global__ __launch_bounds__(256) void softmax256(const float* __restrict__ af,
    bf16_t* __restrict__ ab) {
  const float* ar = af + (size_t)blockIdx.x * MLM;
  int t = threadIdx.x;
  float v = ar[t];
  __shared__ float redm[4], reds[4];
  float m = v;
#pragma unroll
  for (int off = 32; off > 0; off >>= 1) m = fmaxf(m, __shfl_xor(m, off));
  if ((t & 63) == 0) redm[t >> 6] = m;
  __syncthreads();
  m = fmaxf(fmaxf(redm[0], redm[1]), fmaxf(redm[2], redm[3]));
  float p = __expf(v - m);
  float s = p;
#pragma unroll
  for (int off = 32; off > 0; off >>= 1) s += __shfl_xor(s, off);
  if ((t & 63) == 0) reds[t >> 6] = s;
  __syncthreads();
  s = reds[0] + reds[1] + reds[2] + reds[3];
  ab[(size_t)blockIdx.x * MLM + t] = f2bf(p / s);
}

// ------------------------------------------- pinv scalars: global max sums
__global__ void init_scal(unsigned* s) { if (threadIdx.x < 2) s[threadIdx.x] = 0u; }

__global__ __launch_bounds__(256) void colrow_max(const bf16_t* __restrict__ a,
    unsigned* __restrict__ scal) {
  int bh = blockIdx.x;
  int task = blockIdx.y;
  const bf16_t* ab = a + (size_t)bh * MLM * MLM;
  int t = threadIdx.x;
  float s = 0.f;
  if (task == 0) {
    const bf16_t* rp = ab + (size_t)t * MLM;
    for (int j = 0; j < MLM; j += 8) {
      float d[8];
      unp8(rp + j, d);
      s += d[0]; s += d[1]; s += d[2]; s += d[3];
      s += d[4]; s += d[5]; s += d[6]; s += d[7];
    }
  } else {
    for (int i = 0; i < MLM; ++i) s += bf2f(ab[(size_t)i * MLM + t]);
  }
  __shared__ float red[4];
  float m = s;
#pragma unroll
  for (int off = 32; off > 0; off >>= 1) m = fmaxf(m, __shfl_xor(m, off));
  if ((t & 63) == 0) red[t >> 6] = m;
  __syncthreads();
  if (t == 0) {
    m = fmaxf(fmaxf(red[0], red[1]), fmaxf(red[2], red[3]));
    atomicMax(scal + task, __float_as_uint(m));
  }
}

// z0 = a^T / denom (bf16), z0T = a / denom (bf16)
__global__ __launch_bounds__(256) void zinit(const bf16_t* __restrict__ ab,
    bf16_t* __restrict__ z0, bf16_t* __restrict__ z0T,
    const unsigned* __restrict__ scal) {
  size_t idx = (size_t)blockIdx.x * 256 + threadIdx.x;
  float denom = __uint_as_float(scal[0]) * __uint_as_float(scal[1]);
  size_t bh = idx >> 16;
  int i = (int)((idx >> 8) & 255);
  int j = (int)(idx & 255);
  bf16_t r = f2bf(bf2f(ab[idx]) / denom);
  z0T[idx] = r;
  z0[(bh << 16) + ((size_t)j << 8) + i] = r;
}

// --------- attn3v (MFMA flash): partial softmax(q_l@k^T)@v over 512-key chunk
__global__ __launch_bounds__(64) void attn3v_mfma(const bf16_t* __restrict__ qlb,
    const bf16_t* __restrict__ kg, const bf16_t* __restrict__ vT,
    float* __restrict__ pacc, float* __restrict__ pm, float* __restrict__ ps) {
  int bid = blockIdx.x;                       // 0..4095 (4096 % 8 == 0)
  int orig = (bid & 7) * 512 + (bid >> 3);    // XCD-contiguous remap
  int m0 = (orig & 7) << 5;                   // q-row tile
  int cz = (orig >> 3) & 7;                   // 512-key chunk
  int bh = orig >> 6;                         // batch*head
  int lane = threadIdx.x;
  int l15 = lane & 15, l16 = lane >> 4;
  __shared__ short plds[32][136];
  const bf16_t* qbase = qlb + (size_t)bh * MLM * DH;
  const bf16_t* kbase = kg + (size_t)bh * SEQ * DH;
  const bf16_t* vbase = vT + (size_t)bh * DH * SEQ;
  bf16x8 af[2][2];
#pragma unroll
  for (int mt = 0; mt < 2; ++mt)
#pragma unroll
    for (int ks = 0; ks < 2; ++ks)
      af[mt][ks] = *(const bf16x8*)(qbase + (size_t)(m0 + mt * 16 + l15) * DH + ks * 32 + l16 * 8);
  float m_run[2][4], s_run[2][4];
  f32x4 o[2][4];
#pragma unroll
  for (int mt = 0; mt < 2; ++mt) {
#pragma unroll
    for (int rg = 0; rg < 4; ++rg) { m_run[mt][rg] = -1e30f; s_run[mt][rg] = 0.f; }
#pragma unroll
    for (int n2 = 0; n2 < 4; ++n2) o[mt][n2] = (f32x4){0.f, 0.f, 0.f, 0.f};
  }
  int kbeg = cz << 9;
  for (int kt = kbeg; kt < kbeg + 512; kt += 128) {
    f32x4 sacc[2][8];
#pragma unroll
    for (int mt = 0; mt < 2; ++mt)
#pragma unroll
      for (int nt = 0; nt < 8; ++nt) sacc[mt][nt] = (f32x4){0.f, 0.f, 0.f, 0.f};
#pragma unroll
    for (int nt = 0; nt < 8; ++nt) {
      const bf16_t* kr = kbase + (size_t)(kt + nt * 16 + l15) * DH + l16 * 8;
      bf16x8 b0 = *(const bf16x8*)kr;
      bf16x8 b1 = *(const bf16x8*)(kr + 32);
      sacc[0][nt] = __builtin_amdgcn_mfma_f32_16x16x32_bf16(af[0][0], b0, sacc[0][nt], 0, 0, 0);
      sacc[0][nt] = __builtin_amdgcn_mfma_f32_16x16x32_bf16(af[0][1], b1, sacc[0][nt], 0, 0, 0);
      sacc[1][nt] = __builtin_amdgcn_mfma_f32_16x16x32_bf16(af[1][0], b0, sacc[1][nt], 0, 0, 0);
      sacc[1][nt] = __builtin_amdgcn_mfma_f32_16x16x32_bf16(af[1][1], b1, sacc[1][nt], 0, 0, 0);
    }
#pragma unroll
    for (int mt = 0; mt < 2; ++mt)
#pragma unroll
      for (int rg = 0; rg < 4; ++rg) {
        float mx = sacc[mt][0][rg];
#pragma unroll
        for (int nt = 1; nt < 8; ++nt) mx = fmaxf(mx, sacc[mt][nt][rg]);
        mx = fmaxf(mx, __shfl_xor(mx, 1));
        mx = fmaxf(mx, __shfl_xor(mx, 2));
        mx = fmaxf(mx, __shfl_xor(mx, 4));
        mx = fmaxf(mx, __shfl_xor(mx, 8));
        float mnew = fmaxf(m_run[mt][rg], mx);
        float corr = __expf(m_run[mt][rg] - mnew);
        float s = 0.f;
#pragma unroll
        for (int nt = 0; nt < 8; ++nt) {
          float p = __expf(sacc[mt][nt][rg] - mnew);
          sacc[mt][nt][rg] = p;
          s += p;
        }
        s += __shfl_xor(s, 1); s += __shfl_xor(s, 2);
        s += __shfl_xor(s, 4); s += __shfl_xor(s, 8);
        s_run[mt][rg] = s_run[mt][rg] * corr + s;
        m_run[mt][rg] = mnew;
#pragma unroll
        for (int n2 = 0; n2 < 4; ++n2) o[mt][n2][rg] *= corr;
      }
#pragma unroll
    for (int mt = 0; mt < 2; ++mt)
#pragma unroll
      for (int nt = 0; nt < 8; ++nt)
#pragma unroll
        for (int rg = 0; rg < 4; ++rg)
          plds[mt * 16 + l16 * 4 + rg][nt * 16 + l15] = (short)f2bf(sacc[mt][nt][rg]);
#pragma unroll
    for (int ks2 = 0; ks2 < 4; ++ks2) {
      bf16x8 pa0 = *(const bf16x8*)&plds[l15][ks2 * 32 + l16 * 8];
      bf16x8 pa1 = *(const bf16x8*)&plds[16 + l15][ks2 * 32 + l16 * 8];
#pragma unroll
      for (int n2 = 0; n2 < 4; ++n2) {
        bf16x8 vb8 = *(const bf16x8*)(vbase + (size_t)(n2 * 16 + l15) * SEQ + kt + ks2 * 32 + l16 * 8);
        o[0][n2] = __builtin_amdgcn_mfma_f32_16x16x32_bf16(pa0, vb8, o[0][n2], 0, 0, 0);
        o[1][n2] = __builtin_amdgcn_mfma_f32_16x16x32_bf16(pa1, vb8, o[1][n2], 0, 0, 0);
      }
    }
  }
  size_t pidx0 = (size_t)(bh * 8 + cz) * MLM + m0;
#pragma unroll
  for (int mt = 0; mt < 2; ++mt)
#pragma unroll
    for (int n2 = 0; n2 < 4; ++n2)
#pragma unroll
      for (int rg = 0; rg < 4; ++rg) {
        int row = mt * 16 + l16 * 4 + rg;
        pacc[(pidx0 + row) * 64 + n2 * 16 + l15] = o[mt][n2][rg];
      }
  if (l15 == 0) {
#pragma unroll
    for (int mt = 0; mt < 2; ++mt)
#pragma unroll
      for (int rg = 0; rg < 4; ++rg) {
        pm[pidx0 + mt * 16 + l16 * 4 + rg] = m_run[mt][rg];
        ps[pidx0 + mt * 16 + l16 * 4 + rg] = s_run[mt][rg];
      }
  }
}

// --------------- attn3v phase 2: combine 8 chunk-partials -> a3v bf16
__global__ __launch_bounds__(256) void attn3v_comb(const float* __restrict__ pacc,
    const float* __restrict__ pm, const float* __restrict__ ps,
    bf16_t* __restrict__ a3vb) {
  int gw = blockIdx.x * 4 + (threadIdx.x >> 6);  // row id 0..16383
  int lane = threadIdx.x & 63;
  int bh = gw >> 8, row = gw & 255;
  float ms[8];
  float M = -1e30f;
#pragma unroll
  for (int cc = 0; cc < 8; ++cc) {
    ms[cc] = pm[(size_t)(bh * 8 + cc) * MLM + row];
    M = fmaxf(M, ms[cc]);
  }
  float S = 0.f, val = 0.f;
#pragma unroll
  for (int cc = 0; cc < 8; ++cc) {
    size_t pidx = (size_t)(bh * 8 + cc) * MLM + row;
    float w = __expf(ms[cc] - M);
    S += w * ps[pidx];
    val += w * pacc[pidx * 64 + lane];
  }
  a3vb[(size_t)gw * 64 + lane] = f2bf(val / S);
}

// ---------------- wm^T = (zc @ a3v)^T  bf16 [bh][64][256]
__global__ __launch_bounds__(256) void wm_kernel(const bf16_t* __restrict__ zb,
    const bf16_t* __restrict__ a3vb, bf16_t* __restrict__ wmT) {
  int bh = blockIdx.y;
  int m0 = blockIdx.x << 6;
  __shared__ bf16_t a3s[MLM * DH];
  int t = threadIdx.x;
  const bf16_t* asrc = a3vb + (size_t)bh * MLM * DH;
#pragma unroll
  for (int i = 0; i < 8; ++i)
    *(bf16x8*)(a3s + ((size_t)t + 256 * i) * 8) =
        *(const bf16x8*)(asrc + ((size_t)t + 256 * i) * 8);
  __syncthreads();
  int row = m0 + (t >> 2);
  int c0 = (t & 3) * 16;
  const bf16_t* zrow = zb + (size_t)bh * 65536 + (size_t)row * 256;
  float acc16[16] = {};
  for (int k0 = 0; k0 < 256; k0 += 8) {
    float a8[8];
    unp8(zrow + k0, a8);
#pragma unroll
    for (int j = 0; j < 8; ++j) {
      float av[16];
      unp8(a3s + (k0 + j) * 64 + c0, av);
      unp8(a3s + (k0 + j) * 64 + c0 + 8, av + 8);
#pragma unroll
      for (int e = 0; e < 16; ++e) acc16[e] += a8[j] * av[e];
    }
  }
  bf16_t* wd = wmT + (size_t)bh * DH * MLM;
#pragma unroll
  for (int e = 0; e < 16; ++e)
    wd[(size_t)(c0 + e) * MLM + row] = f2bf(acc16[e]);
}

// ---------- attn1 (MFMA): om = softmax(q @ k_l^T) @ W, one wave = 32 q-rows
__global__ __launch_bounds__(64) void attn1_mfma(const bf16_t* __restrict__ qg,
    const bf16_t* __restrict__ klb, const bf16_t* __restrict__ wmT,
    bf16_t* __restrict__ om) {
  int bh = blockIdx.y, bat = bh >> 3, head = bh & 7;
  int m0 = blockIdx.x << 5;
  int lane = threadIdx.x;
  int l15 = lane & 15, l16 = lane >> 4;
  __shared__ short plds[32][264];
  const bf16_t* qbase = qg + (size_t)bh * SEQ * DH;
  const bf16_t* kbase = klb + (size_t)bh * MLM * DH;
  bf16x8 af[2][2];
#pragma unroll
  for (int mt = 0; mt < 2; ++mt)
#pragma unroll
    for (int ks = 0; ks < 2; ++ks)
      af[mt][ks] = *(const bf16x8*)(qbase + (size_t)(m0 + mt * 16 + l15) * DH + ks * 32 + l16 * 8);
  f32x4 acc[2][16];
#pragma unroll
  for (int mt = 0; mt < 2; ++mt)
#pragma unroll
    for (int nt = 0; nt < 16; ++nt) acc[mt][nt] = (f32x4){0.f, 0.f, 0.f, 0.f};
#pragma unroll
  for (int nt = 0; nt < 16; ++nt) {
    bf16x8 b0 = *(const bf16x8*)(kbase + (size_t)(nt * 16 + l15) * DH + l16 * 8);
    bf16x8 b1 = *(const bf16x8*)(kbase + (size_t)(nt * 16 + l15) * DH + 32 + l16 * 8);
    acc[0][nt] = __builtin_amdgcn_mfma_f32_16x16x32_bf16(af[0][0], b0, acc[0][nt], 0, 0, 0);
    acc[0][nt] = __builtin_amdgcn_mfma_f32_16x16x32_bf16(af[0][1], b1, acc[0][nt], 0, 0, 0);
    acc[1][nt] = __builtin_amdgcn_mfma_f32_16x16x32_bf16(af[1][0], b0, acc[1][nt], 0, 0, 0);
    acc[1][nt] = __builtin_amdgcn_mfma_f32_16x16x32_bf16(af[1][1], b1, acc[1][nt], 0, 0, 0);
  }
  float inv[2][4];
#pragma unroll
  for (int mt = 0; mt < 2; ++mt)
#pragma unroll
    for (int rg = 0; rg < 4; ++rg) {
      float mx = acc[mt][0][rg];
#pragma unroll
      for (int nt = 1; nt < 16; ++nt) mx = fmaxf(mx, acc[mt][nt][rg]);
      mx = fmaxf(mx, __shfl_xor(mx, 1));
      mx = fmaxf(mx, __shfl_xor(mx, 2));
      mx = fmaxf(mx, __shfl_xor(mx, 4));
      mx = fmaxf(mx, __shfl_xor(mx, 8));
      float s = 0.f;
#pragma unroll
      for (int nt = 0; nt < 16; ++nt) {
        float p = __expf(acc[mt][nt][rg] - mx);
        acc[mt][nt][rg] = p;
        s += p;
      }
      s += __shfl_xor(s, 1); s += __shfl_xor(s, 2);
      s += __shfl_xor(s, 4); s += __shfl_xor(s, 8);
      inv[mt][rg] = 1.f / s;
    }
#pragma unroll
  for (int mt = 0; mt < 2; ++mt)
#pragma unroll
    for (int nt = 0; nt < 16; ++nt)
#pragma unroll
      for (int rg = 0; rg < 4; ++rg)
        plds[mt * 16 + l16 * 4 + rg][nt * 16 + l15] = (short)f2bf(acc[mt][nt][rg]);
  const bf16_t* wbase = wmT + (size_t)bh * DH * MLM;
  f32x4 o[2][4];
#pragma unroll
  for (int mt = 0; mt < 2; ++mt)
#pragma unroll
    for (int n2 = 0; n2 < 4; ++n2) o[mt][n2] = (f32x4){0.f, 0.f, 0.f, 0.f};
#pragma unroll
  for (int ks = 0; ks < 8; ++ks) {
    bf16x8 pa0 = *(const bf16x8*)&plds[l15][ks * 32 + l16 * 8];
    bf16x8 pa1 = *(const bf16x8*)&plds[16 + l15][ks * 32 + l16 * 8];
#pragma unroll
    for (int n2 = 0; n2 < 4; ++n2) {
      bf16x8 wb = *(const bf16x8*)(wbase + (size_t)(n2 * 16 + l15) * MLM + ks * 32 + l16 * 8);
      o[0][n2] = __builtin_amdgcn_mfma_f32_16x16x32_bf16(pa0, wb, o[0][n2], 0, 0, 0);
      o[1][n2] = __builtin_amdgcn_mfma_f32_16x16x32_bf16(pa1, wb, o[1][n2], 0, 0, 0);
    }
  }
#pragma unroll
  for (int mt = 0; mt < 2; ++mt)
#pragma unroll
    for (int n2 = 0; n2 < 4; ++n2)
#pragma unroll
      for (int rg = 0; rg < 4; ++rg) {
        int n = m0 + mt * 16 + l16 * 4 + rg;
        int d = n2 * 16 + l15;
        om[((size_t)(bat * SEQ + n)) * DMODEL + head * DH + d] =
            f2bf(o[mt][n2][rg] * inv[mt][rg]);
      }
}

// --------------------- depthwise conv added into om (bf16 RMW), reads vT.
// vT slice [64 d][64 n-window] is transposed through LDS into the same
// vs[seq][d] tile as the old v-based version -> bit-identical results.
__global__ __launch_bounds__(256) void conv_add(const bf16_t* __restrict__ vT,
    const float* __restrict__ rk, bf16_t* __restrict__ om) {
  int bh = blockIdx.y, bat = bh >> 3, head = bh & 7;
  int n0 = blockIdx.x << 5;
  __shared__ bf16_t vs[64 * 64];               // [seq-window][d]
  int t = threadIdx.x;
  int d = t & 63;
  int nq = (t >> 6) << 4;                      // 0,16,32,48
  const bf16_t* vrow = vT + ((size_t)bh * DH + d) * SEQ;
#pragma unroll
  for (int h = 0; h < 2; ++h) {
    int nb = n0 - 16 + nq + h * 8;             // global n of first elem
    unsigned short tmp[8];
    if (nb >= 0 && nb + 8 <= SEQ) {
      bf16x8 val = *(const bf16x8*)(vrow + nb);
#pragma unroll
      for (int e = 0; e < 8; ++e) tmp[e] = ((unsigned short*)&val)[e];
    } else {
#pragma unroll
      for (int e = 0; e < 8; ++e) {
        int n = nb + e;
        tmp[e] = (n >= 0 && n < SEQ) ? vrow[n] : (unsigned short)0;
      }
    }
#pragma unroll
    for (int e = 0; e < 8; ++e) vs[(nq + h * 8 + e) * 64 + d] = tmp[e];
  }
  __syncthreads();
  float w[33];
#pragma unroll
  for (int i = 0; i < 33; ++i) w[i] = rk[head * 33 + i];
  int r0 = (t >> 6) << 3;
  float out[8] = {0.f, 0.f, 0.f, 0.f, 0.f, 0.f, 0.f, 0.f};
#pragma unroll
  for (int j = 0; j < 40; ++j) {
    float vv = bf2f(vs[(r0 + j) * 64 + d]);
    int ilo = j - 32; if (ilo < 0) ilo = 0;
    int ihi = j; if (ihi > 7) ihi = 7;
    for (int i = ilo; i <= ihi; ++i) out[i] += w[j - i] * vv;
  }
#pragma unroll
  for (int i = 0; i < 8; ++i) {
    int n = n0 + r0 + i;
    size_t idx = ((size_t)(bat * SEQ + n)) * DMODEL + head * DH + d;
    om[idx] = f2bf(bf2f(om[idx]) + out[i]);
  }
}

// ---------------------------------------------------------------- launcher
extern "C" void kernel_launch(void* const* d_in, const int* in_sizes, int n_in,
                              void* d_out, int out_size, void* d_ws, size_t ws_size,
                              hipStream_t stream) {
  const float* x     = (const float*)d_in[0];
  const float* gamma = (const float*)d_in[1];
  const float* beta  = (const float*)d_in[2];
  const float* w_qkv = (const float*)d_in[3];
  const float* w_out = (const float*)d_in[4];
  const float* b_out = (const float*)d_in[5];
  const float* rk    = (const float*)d_in[6];
  float* y  = (float*)d_out;

  // ---- workspace layout (221.3 MB total) ----
  bf16_t* xnb  = (bf16_t*)d_ws;           // 16777216 (reused as om)
  bf16_t* qb   = xnb + 16777216;
  bf16_t* kb   = qb + 16777216;
  bf16_t* vTb  = kb + 16777216;           // vT [bh][64][4096] (was vb; v dropped)
  bf16_t* wqkvT = vTb + 16777216;         // 786432
  bf16_t* woutT = wqkvT + 786432;         // 262144
  bf16_t* qlb  = woutT + 262144;          // 1048576
  bf16_t* klb  = qlb + 1048576;           // 1048576
  bf16_t* a2b  = klb + 1048576;           // 4194304
  // NS slots (4 x 4194304): zA/zB (z ping-pong), Ya/Yb (Y ping-pong)
  bf16_t* zA   = a2b + 4194304;
  bf16_t* z0T  = zA + 4194304;            // z0T for Y0 GEMM; then reused as Yb
  bf16_t* zB   = z0T + 4194304;
  bf16_t* Ya   = zB + 4194304;
  bf16_t* Yb   = z0T;                     // alias (z0T dead after Y0 GEMM)
  bf16_t* a3vb = Ya + 4194304;            // 1048576
  bf16_t* wmT  = a3vb + 1048576;          // 1048576
  // shared region SR (33.55 MB): a2f32 -> pacc -> {YTa, YTb, t2T, t1T}
  float*  SR   = (float*)(wmT + 1048576); // 8388608 f32
  float*  a2f  = SR;
  float*  pacc = SR;
  bf16_t* YTa  = (bf16_t*)SR;
  bf16_t* YTb  = YTa + 4194304;
  bf16_t* t2T  = YTa + 8388608;
  bf16_t* t1T  = YTa + 12582912;
  float*  pm   = SR + 8388608;            // 131072
  float*  ps   = pm + 131072;             // 131072
  unsigned* scal = (unsigned*)(ps + 131072);
  size_t need = (size_t)93323264 * 2 + (size_t)(8388608 + 262144) * 4 + 64;
  if (ws_size < need) return;  // clean fail instead of OOB fault

  ln_kernel<<<NROWS, 64, 0, stream>>>(x, gamma, beta, xnb);
  convT<<<3072, 256, 0, stream>>>(w_qkv, wqkvT, 512, 1536);
  convT<<<1024, 256, 0, stream>>>(w_out, woutT, 512, 512);

  // QKV projection with fused landmark pooling (pool_kernel eliminated)
  gemm_qkv_256<<<768, 512, 0, stream>>>(xnb, wqkvT, qb, kb, vTb, qlb, klb);

  // sim2 = q_l @ k_l^T (32-tile MFMA, f32 out), softmax -> a2b bf16
  bmm_mfma32<<<4096, 256, 0, stream>>>(qlb, klb, nullptr, nullptr, a2f,
      64, 1.f, 0.f, 0.f, 4);
  softmax256<<<NBH * MLM, 256, 0, stream>>>(a2f, a2b);

  init_scal<<<1, 64, 0, stream>>>(scal);
  colrow_max<<<dim3(NBH, 2), 256, 0, stream>>>(a2b, scal);

  // attn3v split-K MFMA flash
  attn3v_mfma<<<4096, 64, 0, stream>>>(qlb, kb, vTb, pacc, pm, ps);
  attn3v_comb<<<4096, 256, 0, stream>>>(pacc, pm, ps, a3vb);

  // pinv via Y-tracking chain, 32-tile GEMMs
  zinit<<<16384, 256, 0, stream>>>(a2b, zA, z0T, scal);
  // Y0 = a2 @ z0  (= a2@a2^T/c): A=a2, BT=z0T -> Ya + YTa
  bmm_mfma32<<<4096, 256, 0, stream>>>(a2b, z0T, Ya, YTa, nullptr,
      256, 1.f, 0.f, 0.f, 3);
  bf16_t* zc = zA;  bf16_t* zo = zB;
  bf16_t* Yc = Ya;  bf16_t* YTc = YTa;
  bf16_t* Yo = Yb;  bf16_t* YTo = YTb;
  for (int it = 0; it < 6; ++it) {
    // t2 = Y@Y - 7Y + 15I  -> t2T
    bmm_mfma32<<<4096, 256, 0, stream>>>(Yc, YTc, nullptr, t2T, nullptr,
        256, 1.f, -7.f, 15.f, 2);
    // t1 = 13I - Y@t2      -> t1T
    bmm_mfma32<<<4096, 256, 0, stream>>>(Yc, t2T, nullptr, t1T, nullptr,
        256, -1.f, 0.f, 13.f, 2);
    // z' = 0.25 z@t1 ; Y' = 0.25 Y@t1 (merged, 8192 blocks)
    ns_zy32<<<8192, 256, 0, stream>>>(zc, Yc, t1T, zo, Yo, YTo);
    bf16_t* tp;
    tp = zc; zc = zo; zo = tp;
    tp = Yc; Yc = Yo; Yo = tp;
    tp = YTc; YTc = YTo; YTo = tp;
  }
  // zc == zA after even number of swaps

  // wm^T = (z6 @ a3v)^T
  wm_kernel<<<dim3(4, NBH), 256, 0, stream>>>(zc, a3vb, wmT);

  // attn1 (MFMA) -> om, then depthwise conv added (reads vT)
  bf16_t* om = xnb;
  attn1_mfma<<<dim3(SEQ / 32, NBH), 64, 0, stream>>>(qb, klb, wmT, om);
  conv_add<<<dim3(SEQ / 32, NBH), 256, 0, stream>>>(vTb, rk, om);

  // y = x + om @ w_out + b_out
  gemm_out_mfma<<<1024, 256, 0, stream>>>(om, woutT, b_out, x, y);
}